// Round 6
// baseline (416.840 us; speedup 1.0000x reference)
//
#include <hip/hip_runtime.h>

// ---------------------------------------------------------------------------
// BiMamba2 (D_MODEL=1024, D_INNER=2048, NHEADS=32, HEADDIM=64, D_STATE=128,
// D_CONV=4, B=4, L=1024).  Pipeline:
//   ln1 -> (bf16) -> GEMM1 (in-proj, shared both dirs) -> conv (per dir)
//   -> dtprep -> chunked MFMA scan (frag-linear LDS, async-pipelined)
//   -> gate+RMS+combine -> GEMM2 -> ln2
// ---------------------------------------------------------------------------

#define BSZ 4
#define SEQ 1024
#define DMODEL 1024
#define DINNER 2048
#define NHEADS 32
#define HEADDIM 64
#define DSTATE 128
#define CONVDIM 2304            // DINNER + 2*DSTATE
#define DPROJ 4384              // 2*DINNER + 2*DSTATE + NHEADS
#define DPROJ_PAD 4480          // padded to multiple of 128
#define NTOK (BSZ*SEQ)          // 4096
#define EPSF 1e-5f
#define CH 32                   // scan chunk length
#define NCHK (SEQ/CH)           // 32 chunks

typedef float f32x4 __attribute__((ext_vector_type(4)));
typedef __bf16 bf16x8 __attribute__((ext_vector_type(8)));

__device__ __forceinline__ unsigned short f2bf(float f) {
  unsigned int x = __float_as_uint(f);
  unsigned int r = (x + 0x7fffu + ((x >> 16) & 1u)) >> 16;
  return (unsigned short)r;
}
__device__ __forceinline__ float bf2f(unsigned short u) {
  return __uint_as_float(((unsigned int)u) << 16);
}

__device__ __forceinline__ void async_load16(const void* g, void* l) {
  __builtin_amdgcn_global_load_lds(
      (const __attribute__((address_space(1))) void*)g,
      (__attribute__((address_space(3))) void*)l, 16, 0, 0);
}

// ---------------------------------------------------------------------------
// Prep: weight conversion (merged) + lengths
// ---------------------------------------------------------------------------
#define W1N (DPROJ_PAD * DMODEL)
#define W2N (DMODEL * DINNER)
__global__ void k_convert(const float* __restrict__ w1, const float* __restrict__ w2,
                          unsigned short* __restrict__ o1, unsigned short* __restrict__ o2) {
  int idx = blockIdx.x * 256 + threadIdx.x;
  if (idx < W1N) {
    int row = idx >> 10, col = idx & 1023;
    float v = (row < DPROJ) ? w1[(size_t)row * DMODEL + col] : 0.f;
    o1[idx] = f2bf(v);
  } else {
    int k = idx - W1N;
    o2[k] = f2bf(w2[k]);
  }
}
__global__ void k_lengths(const unsigned char* __restrict__ mask, int* __restrict__ lengths) {
  int b = blockIdx.x, tid = threadIdx.x;
  int cnt = 0;
  for (int k = 0; k < 4; ++k)
    cnt += (mask[(size_t)b * SEQ + tid + k * 256] == 0) ? 1 : 0;
  for (int o = 32; o > 0; o >>= 1) cnt += __shfl_down(cnt, o);
  __shared__ int red[4];
  if ((tid & 63) == 0) red[tid >> 6] = cnt;
  __syncthreads();
  if (tid == 0) lengths[b] = red[0] + red[1] + red[2] + red[3];
}

// ---------------------------------------------------------------------------
// LayerNorm (1024 wide) -> bf16 out
// ---------------------------------------------------------------------------
__global__ __launch_bounds__(256) void k_ln_bf16(const float* __restrict__ in,
                                                 unsigned short* __restrict__ out) {
  int row = blockIdx.x, tid = threadIdx.x;
  float4 v = ((const float4*)(in + (size_t)row * DMODEL))[tid];
  float s = v.x + v.y + v.z + v.w;
  float ss = v.x * v.x + v.y * v.y + v.z * v.z + v.w * v.w;
  for (int o = 32; o > 0; o >>= 1) { s += __shfl_down(s, o); ss += __shfl_down(ss, o); }
  __shared__ float red[8];
  if ((tid & 63) == 0) { red[tid >> 6] = s; red[4 + (tid >> 6)] = ss; }
  __syncthreads();
  s = red[0] + red[1] + red[2] + red[3];
  ss = red[4] + red[5] + red[6] + red[7];
  float mu = s * (1.f / DMODEL);
  float var = ss * (1.f / DMODEL) - mu * mu;
  float rs = rsqrtf(var + EPSF);
  ushort4 o;
  o.x = f2bf((v.x - mu) * rs); o.y = f2bf((v.y - mu) * rs);
  o.z = f2bf((v.z - mu) * rs); o.w = f2bf((v.w - mu) * rs);
  ((ushort4*)(out + (size_t)row * DMODEL))[tid] = o;
}

// LayerNorm (1024 wide) -> fp32 out (final)
__global__ __launch_bounds__(256) void k_ln_f32(const float* __restrict__ in,
                                                float* __restrict__ out) {
  int row = blockIdx.x, tid = threadIdx.x;
  float4 v = ((const float4*)(in + (size_t)row * DMODEL))[tid];
  float s = v.x + v.y + v.z + v.w;
  float ss = v.x * v.x + v.y * v.y + v.z * v.z + v.w * v.w;
  for (int o = 32; o > 0; o >>= 1) { s += __shfl_down(s, o); ss += __shfl_down(ss, o); }
  __shared__ float red[8];
  if ((tid & 63) == 0) { red[tid >> 6] = s; red[4 + (tid >> 6)] = ss; }
  __syncthreads();
  s = red[0] + red[1] + red[2] + red[3];
  ss = red[4] + red[5] + red[6] + red[7];
  float mu = s * (1.f / DMODEL);
  float var = ss * (1.f / DMODEL) - mu * mu;
  float rs = rsqrtf(var + EPSF);
  float4 o;
  o.x = (v.x - mu) * rs; o.y = (v.y - mu) * rs;
  o.z = (v.z - mu) * rs; o.w = (v.w - mu) * rs;
  ((float4*)(out + (size_t)row * DMODEL))[tid] = o;
}

// ---------------------------------------------------------------------------
// bf16 MFMA GEMM (B^T form): C[M,N] = A[M,K] * B[N,K]^T, fp32 out.
// ---------------------------------------------------------------------------
__global__ __launch_bounds__(256) void k_gemm_bt(const unsigned short* __restrict__ A,
                                                 const unsigned short* __restrict__ B,
                                                 float* __restrict__ C,
                                                 int K, int lda, int ldb, int ldc) {
  __shared__ unsigned short Asm[128 * 32];
  __shared__ unsigned short Bsm[128 * 32];
  const int tid = threadIdx.x;
  const int lane = tid & 63;
  const int w = tid >> 6;
  const int wm = w >> 1, wn = w & 1;
  const long m0 = (long)blockIdx.x * 128;
  const long n0 = (long)blockIdx.y * 128;

  const int sr = lane >> 2;
  const int sc = (lane & 3) * 8;
  const unsigned short* gA0 = A + (m0 + (w * 2 + 0) * 16 + sr) * (long)lda + sc;
  const unsigned short* gA1 = A + (m0 + (w * 2 + 1) * 16 + sr) * (long)lda + sc;
  const unsigned short* gB0 = B + (n0 + (w * 2 + 0) * 16 + sr) * (long)ldb + sc;
  const unsigned short* gB1 = B + (n0 + (w * 2 + 1) * 16 + sr) * (long)ldb + sc;
  unsigned short* lA0 = Asm + (w * 2 + 0) * 512;
  unsigned short* lA1 = Asm + (w * 2 + 1) * 512;
  unsigned short* lB0 = Bsm + (w * 2 + 0) * 512;
  unsigned short* lB1 = Bsm + (w * 2 + 1) * 512;

  f32x4 acc[4][4] = {};
  const int q8 = (lane >> 4) * 8;
  const int r16 = lane & 15;

  for (int k0 = 0; k0 < K; k0 += 32) {
    async_load16(gA0 + k0, lA0);
    async_load16(gA1 + k0, lA1);
    async_load16(gB0 + k0, lB0);
    async_load16(gB1 + k0, lB1);
    __syncthreads();
    bf16x8 af[4], bfr[4];
#pragma unroll
    for (int i = 0; i < 4; ++i)
      af[i] = *reinterpret_cast<const bf16x8*>(Asm + (wm * 64 + i * 16 + r16) * 32 + q8);
#pragma unroll
    for (int j = 0; j < 4; ++j)
      bfr[j] = *reinterpret_cast<const bf16x8*>(Bsm + (wn * 64 + j * 16 + r16) * 32 + q8);
#pragma unroll
    for (int i = 0; i < 4; ++i)
#pragma unroll
      for (int j = 0; j < 4; ++j)
        acc[i][j] = __builtin_amdgcn_mfma_f32_16x16x32_bf16(af[i], bfr[j], acc[i][j], 0, 0, 0);
    __syncthreads();
  }
  const int q = lane >> 4, cn = lane & 15;
#pragma unroll
  for (int i = 0; i < 4; ++i)
#pragma unroll
    for (int j = 0; j < 4; ++j) {
      long crow = m0 + wm * 64 + i * 16 + q * 4;
      long ccol = n0 + wn * 64 + j * 16 + cn;
#pragma unroll
      for (int r = 0; r < 4; ++r)
        C[(crow + r) * (long)ldc + ccol] = acc[i][j][r];
    }
}

// ---------------------------------------------------------------------------
// Depthwise causal conv (width 4) + SiLU over xBC slice -> bf16.
// ---------------------------------------------------------------------------
__global__ __launch_bounds__(256) void k_conv(
    const float* __restrict__ zx,
    const float* __restrict__ cw_f, const float* __restrict__ cb_f,
    const float* __restrict__ cw_r, const float* __restrict__ cb_r,
    const int* __restrict__ lengths,
    __bf16* __restrict__ xb) {
  const int bx = blockIdx.x;                // (dir*4+b)*1024 + t
  const int t = bx & 1023;
  const int db = bx >> 10;
  const int b = db & 3;
  const int dir = db >> 2;
  const int tid = threadIdx.x;
  const int len = lengths[b];

  const float* cw = dir ? cw_r : cw_f;
  const float* cb = dir ? cb_r : cb_f;

  const float* rows[4];
#pragma unroll
  for (int j = 0; j < 4; ++j) {
    int tt = t - 3 + j;
    if (tt < 0) { rows[j] = nullptr; }
    else {
      int s = dir ? ((tt < len) ? (len - 1 - tt) : tt) : tt;
      rows[j] = zx + ((size_t)b * SEQ + s) * DPROJ_PAD;
    }
  }
  __bf16* orow = xb + ((size_t)db * SEQ + t) * CONVDIM;

#pragma unroll
  for (int k = 0; k < 9; ++k) {             // 2304 = 9*256
    int c = tid + k * 256;
    float4 w4 = *(const float4*)(cw + (size_t)c * 4);
    float acc = cb[c];
    if (rows[0]) acc = fmaf(w4.x, rows[0][DINNER + c], acc);
    if (rows[1]) acc = fmaf(w4.y, rows[1][DINNER + c], acc);
    if (rows[2]) acc = fmaf(w4.z, rows[2][DINNER + c], acc);
    if (rows[3]) acc = fmaf(w4.w, rows[3][DINNER + c], acc);
    float sig = 1.f / (1.f + __expf(-acc));
    orow[c] = (__bf16)(acc * sig);
  }
}

// ---------------------------------------------------------------------------
// dt/decay table precompute.  One thread per (db,h,chunk): 8192 threads.
// Layout ddg[(db*32+h)*32 + chunk][128]: [0:32)=dt, [32:64)=cd=A*cum,
// [64:96)=W=dt*e^{A(cum31-cum)}, [96:128)=P=e^{A*cum}.
// ---------------------------------------------------------------------------
__global__ __launch_bounds__(256) void k_dtprep(
    const float* __restrict__ zx,
    const float* __restrict__ dtb_f, const float* __restrict__ dtb_r,
    const float* __restrict__ al_f, const float* __restrict__ al_r,
    const int* __restrict__ lengths, float* __restrict__ ddg) {
  int t = blockIdx.x * 256 + threadIdx.x;   // (db*32+h)*32 + chunk
  int chunk = t & 31, hh = (t >> 5) & 31, db = t >> 10;
  int b = db & 3, dir = db >> 2;
  int len = lengths[b];
  float dtbv = (dir ? dtb_r : dtb_f)[hh];
  float Ah = -__expf((dir ? al_r : al_f)[hh]);
  float dt[32], cums[32];
  float cum = 0.f;
#pragma unroll
  for (int j = 0; j < 32; ++j) {
    int s = chunk * 32 + j;
    int sf = dir ? ((s < len) ? (len - 1 - s) : s) : s;
    float raw = zx[(size_t)(b * SEQ + sf) * DPROJ_PAD + DINNER + CONVDIM + hh] + dtbv;
    float d = (raw > 20.f) ? raw : log1pf(__expf(raw));
    dt[j] = d; cum += d; cums[j] = cum;
  }
  float* o = ddg + (size_t)t * 128;
#pragma unroll
  for (int j = 0; j < 32; ++j) {
    o[j]      = dt[j];
    o[32 + j] = Ah * cums[j];
    o[64 + j] = dt[j] * __expf(Ah * (cum - cums[j]));
    o[96 + j] = __expf(Ah * cums[j]);
  }
}

// ---------------------------------------------------------------------------
// Chunked MFMA selective scan, frag-linear LDS edition.
// One block per (dir,b,h): 256 blocks x 256 threads (4 waves, wave w owns
// p rows w*16..w*16+15).
//
// All MFMA operand tiles live in LDS in FRAG-LINEAR order: a 16xK tile is
// stored as 64 chunks of 16B at  base + chunk*16, chunk = tile*64 + lane,
// where lane (q=lane>>4, l15=lane&15) holds row l15, k = q*8..q*8+7.
// -> every frag read/write is ds_read_b128/ds_write_b128 at base+lane*16:
//    conflict-free by construction, and identical to the global_load_lds
//    destination pattern, so B/C tiles stage DIRECTLY via async with a
//    computed per-lane source (no VALU repack).
// Per chunk: G = C@B^T split across waves (quadrants; upper quadrant is
// static 0); S = G.*decay (+D on diagonal -> absorbs the D*x epilogue);
// y^T = X^T@S^T + (H@C^T).*P; H = atot*H + (X.*W)^T@B.
// X^T A-frag comes straight from global (8 scalar bf16 loads/lane).
// B^T built by an in-LDS repack from a row-major async copy.
// Double-buffered staging issued during compute (m97-style).
// ---------------------------------------------------------------------------
__global__ __launch_bounds__(256) void k_scan(
    const __bf16* __restrict__ xb, const float* __restrict__ ddg,
    const float* __restrict__ D_f, const float* __restrict__ D_r,
    unsigned short* __restrict__ y) {
  __shared__ __bf16 Crawf[2][4096];   // C frag-linear, 8 tiles (tt,kk)
  __shared__ __bf16 Brawf[2][4096];   // B frag-linear (B-as-rows x k=n)
  __shared__ __bf16 Braw2[2][4096];   // B row-major [s][n] (for BT repack)
  __shared__ __bf16 BTf[4096];        // B^T frag-linear, 8 tiles (ng)
  __shared__ float  ddL[2][128];      // dt/cd/W/P tables
  __shared__ __bf16 SL[1024];         // S frag-linear, 2 tiles (t-halves)
  __shared__ __bf16 HL[4][2048];      // per-wave H frag-linear, 4 tiles (kk)
  __shared__ __bf16 yO[2][32 * 72];   // y chunk [t][p], stride 72

  const int bx = blockIdx.x;          // db*32 + h
  const int h = bx & 31;
  const int db = bx >> 5;
  const int dir = db >> 2;
  const int tid = threadIdx.x;
  const int lane = tid & 63;
  const int w = tid >> 6;
  const int l15 = lane & 15;
  const int q = lane >> 4;

  const float Dh = (dir ? D_r : D_f)[h];
  const __bf16* xbase = xb + (size_t)db * SEQ * CONVDIM;
  const float* ddbase = ddg + (size_t)bx * NCHK * 128;
  unsigned short* ybase = y + (size_t)db * SEQ * DINNER + h * HEADDIM;

  // zero H and S (upper-right S quadrant stays 0 forever)
  for (int i = lane; i < 2048; i += 64) HL[w][i] = (__bf16)0.f;
  for (int i = tid; i < 1024; i += 256) SL[i] = (__bf16)0.f;

  f32x4 accH[8] = {};

  // ---- async staging of chunk c into buffer nb (24 wave-loads + dd) ----
  auto issue = [&](int c, int nb) {
    const __bf16* xr = xbase + (size_t)c * CH * CONVDIM;
#pragma unroll
    for (int k = 0; k < 2; ++k) {
      const int idx = w * 2 + k;              // 0..7
      const int P = idx * 64 + lane;
      // frag-linear B/C: chunk P -> row tt*16+l, col kk*32+qq*8
      const int tt = P >> 8, kk = (P >> 6) & 3, qq = (P >> 4) & 3, ll = P & 15;
      const __bf16* gB = xr + (size_t)(tt * 16 + ll) * CONVDIM + DINNER + kk * 32 + qq * 8;
      async_load16(gB, &Brawf[nb][idx * 512]);
      async_load16(gB + 128, &Crawf[nb][idx * 512]);
      // row-major B copy: chunk P -> row P>>4, col (P&15)*8
      const int s = P >> 4, n8 = P & 15;
      const __bf16* g2 = xr + (size_t)s * CONVDIM + DINNER + n8 * 8;
      async_load16(g2, &Braw2[nb][idx * 512]);
    }
    if (w == 3 && lane < 32)
      async_load16(ddbase + (size_t)c * 128 + lane * 4, &ddL[nb][0]);
  };

  issue(0, 0);
  __syncthreads();

  for (int c = 0; c < NCHK; ++c) {
    const int cb = c & 1, nb = cb ^ 1;
    const int s0 = c * CH;

    // ---------------- phase 1 ----------------
    // x A-frag straight from global: lane (q,l15) of wave w needs
    // X^T[p=w*16+l15][s=q*8+j]
    bf16x8 xt;
    {
      const __bf16* gx = xbase + (size_t)(s0 + q * 8) * CONVDIM + h * HEADDIM + w * 16 + l15;
#pragma unroll
      for (int j = 0; j < 8; ++j) xt[j] = gx[(size_t)j * CONVDIM];
    }

    // flush previous chunk's y (coalesced)
    if (c > 0) {
      const int tf = tid >> 3, p8 = (tid & 7) * 8;
      bf16x8 vy = *(const bf16x8*)&yO[nb][tf * 72 + p8];
      *(bf16x8*)(ybase + (size_t)((c - 1) * CH + tf) * DINNER + p8) = vy;
    }

    // B^T repack from row-major Braw2 (column reads 2-way, b128 writes free)
    {
      const int n = tid & 127, sg = tid >> 7;
#pragma unroll
      for (int e = 0; e < 2; ++e) {
        const int qp = sg * 2 + e;            // q' = s>>3
        bf16x8 v;
#pragma unroll
        for (int j = 0; j < 8; ++j) v[j] = Braw2[cb][(qp * 8 + j) * 128 + n];
        *(bf16x8*)&BTf[((n >> 4) * 64 + qp * 16 + (n & 15)) * 8] = v;
      }
    }

    // C frags (all waves, reused in y_inter); G quadrant + mask (waves 0-2)
    bf16x8 Cf0[4], Cf1[4];
#pragma unroll
    for (int kk = 0; kk < 4; ++kk) {
      Cf0[kk] = *(const bf16x8*)&Crawf[cb][(kk * 64 + lane) * 8];
      Cf1[kk] = *(const bf16x8*)&Crawf[cb][((4 + kk) * 64 + lane) * 8];
    }
    if (w < 3) {
      const int tt = (w == 0) ? 0 : 1;
      const int ss = (w == 2) ? 1 : 0;
      f32x4 G = {};
#pragma unroll
      for (int kk = 0; kk < 4; ++kk) {
        bf16x8 Bq = *(const bf16x8*)&Brawf[cb][((ss * 4 + kk) * 64 + lane) * 8];
        G = __builtin_amdgcn_mfma_f32_16x16x32_bf16(tt ? Cf1[kk] : Cf0[kk], Bq, G, 0, 0, 0);
      }
      const int sgl = ss * 16 + l15;
      const float sdt = ddL[cb][sgl];
      const float scd = ddL[cb][32 + sgl];
#pragma unroll
      for (int r = 0; r < 4; ++r) {
        const int t0 = q * 4 + r;
        float v = G[r] * sdt * __expf(ddL[cb][32 + tt * 16 + t0] - scd);
        if (tt == ss) {                        // triangular quadrant
          if (t0 < l15) v = 0.f;
          else if (t0 == l15) v += Dh;         // absorb D*x into S diagonal
        }
        SL[(tt * 64 + (ss * 2 + (l15 >> 3)) * 16 + t0) * 8 + (l15 & 7)] = (__bf16)v;
      }
    }
    __syncthreads();   // barrier A

    // ---------------- phase 2 ----------------
    if (c + 1 < NCHK) issue(c + 1, nb);       // overlap with compute below

    // y_intra: y^T[p][t] = X^T @ S^T
    f32x4 accy0 = {}, accy1 = {};
    {
      bf16x8 S0 = *(const bf16x8*)&SL[(lane) * 8];
      bf16x8 S1 = *(const bf16x8*)&SL[(64 + lane) * 8];
      accy0 = __builtin_amdgcn_mfma_f32_16x16x32_bf16(xt, S0, accy0, 0, 0, 0);
      accy1 = __builtin_amdgcn_mfma_f32_16x16x32_bf16(xt, S1, accy1, 0, 0, 0);
    }
    // y_inter: (H_prev @ C^T) .* P_t
    {
      f32x4 ai0 = {}, ai1 = {};
#pragma unroll
      for (int kk = 0; kk < 4; ++kk) {
        bf16x8 Hf = *(const bf16x8*)&HL[w][(kk * 64 + lane) * 8];
        ai0 = __builtin_amdgcn_mfma_f32_16x16x32_bf16(Hf, Cf0[kk], ai0, 0, 0, 0);
        ai1 = __builtin_amdgcn_mfma_f32_16x16x32_bf16(Hf, Cf1[kk], ai1, 0, 0, 0);
      }
      const float P0 = ddL[cb][96 + l15], P1 = ddL[cb][96 + 16 + l15];
      accy0 = accy0 + ai0 * P0;
      accy1 = accy1 + ai1 * P1;
    }
    // H update: H = atot*H + (X.*W)^T @ B
    {
      const float atot = ddL[cb][96 + 31];
      bf16x8 xw;
#pragma unroll
      for (int j = 0; j < 8; ++j)
        xw[j] = (__bf16)((float)xt[j] * ddL[cb][64 + q * 8 + j]);
#pragma unroll
      for (int nt = 0; nt < 8; ++nt) {
        bf16x8 Bt = *(const bf16x8*)&BTf[(nt * 64 + lane) * 8];
        accH[nt] = accH[nt] * atot;
        accH[nt] = __builtin_amdgcn_mfma_f32_16x16x32_bf16(xw, Bt, accH[nt], 0, 0, 0);
      }
      // bf16 copy into frag-linear HL for next chunk's y_inter (wave-private)
#pragma unroll
      for (int nt = 0; nt < 8; ++nt)
#pragma unroll
        for (int r = 0; r < 4; ++r) {
          const int n = nt * 16 + l15;
          HL[w][((n >> 5) * 64 + ((n & 31) >> 3) * 16 + q * 4 + r) * 8 + (n & 7)] =
              (__bf16)accH[nt][r];
        }
    }
    // stage y chunk (D*x already inside S diagonal)
#pragma unroll
    for (int r = 0; r < 4; ++r) {
      const int p = w * 16 + q * 4 + r;
      yO[cb][l15 * 72 + p]        = (__bf16)accy0[r];
      yO[cb][(16 + l15) * 72 + p] = (__bf16)accy1[r];
    }
    __syncthreads();   // barrier B (also drains async staging for c+1)
  }
  {  // final flush
    const int tf = tid >> 3, p8 = (tid & 7) * 8;
    bf16x8 vy = *(const bf16x8*)&yO[(NCHK - 1) & 1][tf * 72 + p8];
    *(bf16x8*)(ybase + (size_t)((NCHK - 1) * CH + tf) * DINNER + p8) = vy;
  }
}

// ---------------------------------------------------------------------------
// Gate (y * silu(z)) + RMSNorm per direction + average-with-flip -> bf16.
// ---------------------------------------------------------------------------
__global__ __launch_bounds__(256) void k_gate_combine(
    const float* __restrict__ zx, const unsigned short* __restrict__ y,
    const float* __restrict__ nw_f, const float* __restrict__ nw_r,
    const int* __restrict__ lengths, unsigned short* __restrict__ comb) {
  const int bx = blockIdx.x;            // b*SEQ + l
  const int b = bx >> 10, l = bx & 1023;
  const int tid = threadIdx.x;
  const int len = lengths[b];
  const int pos = (l < len) ? (len - 1 - l) : l;
  const float* z = zx + (size_t)bx * DPROJ_PAD;
  const unsigned short* yf = y + ((size_t)b * SEQ + l) * DINNER;
  const unsigned short* yr = y + ((size_t)(BSZ + b) * SEQ + pos) * DINNER;

  float gf[8], gr[8];
  float sf = 0.f, sr = 0.f;
#pragma unroll
  for (int k = 0; k < 8; ++k) {
    int c = tid + k * 256;
    float zz = z[c];
    float sz = zz / (1.f + __expf(-zz));
    float vf = bf2f(yf[c]) * sz;
    float vr = bf2f(yr[c]) * sz;
    gf[k] = vf; gr[k] = vr;
    sf += vf * vf; sr += vr * vr;
  }
  for (int o = 32; o > 0; o >>= 1) { sf += __shfl_down(sf, o); sr += __shfl_down(sr, o); }
  __shared__ float red[8];
  if ((tid & 63) == 0) { red[tid >> 6] = sf; red[4 + (tid >> 6)] = sr; }
  __syncthreads();
  sf = red[0] + red[1] + red[2] + red[3];
  sr = red[4] + red[5] + red[6] + red[7];
  float rf = rsqrtf(sf * (1.f / DINNER) + EPSF);
  float rr = rsqrtf(sr * (1.f / DINNER) + EPSF);
#pragma unroll
  for (int k = 0; k < 8; ++k) {
    int c = tid + k * 256;
    float o = 0.5f * (gf[k] * rf * nw_f[c] + gr[k] * rr * nw_r[c]);
    comb[(size_t)bx * DINNER + c] = f2bf(o);
  }
}

// ---------------------------------------------------------------------------
extern "C" void kernel_launch(void* const* d_in, const int* in_sizes, int n_in,
                              void* d_out, int out_size, void* d_ws, size_t ws_size,
                              hipStream_t stream) {
  const float* hidden      = (const float*)d_in[0];
  const unsigned char* msk = (const unsigned char*)d_in[1];
  const float* in_proj_w   = (const float*)d_in[2];
  const float* out_proj_w  = (const float*)d_in[3];
  const float* conv_w_f    = (const float*)d_in[4];
  const float* conv_b_f    = (const float*)d_in[5];
  const float* dt_bias_f   = (const float*)d_in[6];
  const float* A_log_f     = (const float*)d_in[7];
  const float* D_f         = (const float*)d_in[8];
  const float* norm_w_f    = (const float*)d_in[9];
  const float* conv_w_r    = (const float*)d_in[10];
  const float* conv_b_r    = (const float*)d_in[11];
  const float* dt_bias_r   = (const float*)d_in[12];
  const float* A_log_r     = (const float*)d_in[13];
  const float* D_r         = (const float*)d_in[14];
  const float* norm_w_r    = (const float*)d_in[15];
  float* outF = (float*)d_out;

  char* ws = (char*)d_ws;
  size_t o_w1b  = 0;                         // bf16 [4480][1024]
  size_t o_w2b  = o_w1b  + 9175040;          // bf16 [1024][2048]
  size_t o_hb   = o_w2b  + 4194304;          // bf16 [4096][1024]
  size_t o_zx   = o_hb   + 8388608;          // f32  [4096][4480]
  size_t o_xb   = o_zx   + 73400320;         // bf16 [2][4096][2304]
  size_t o_dd   = o_xb   + 37748736;         // f32  [8192][128]
  size_t o_y    = o_dd   + 4194304;          // bf16 [2][4096][2048]
  size_t o_comb = o_y    + 33554432;         // bf16 [4096][2048]
  size_t o_outp = o_comb + 16777216;         // f32  [4096][1024]
  size_t o_len  = o_outp + 16777216;         // int  [4]

  unsigned short* W1b  = (unsigned short*)(ws + o_w1b);
  unsigned short* W2b  = (unsigned short*)(ws + o_w2b);
  unsigned short* hb   = (unsigned short*)(ws + o_hb);
  float*          zx   = (float*)(ws + o_zx);
  __bf16*         xb   = (__bf16*)(ws + o_xb);
  float*          ddg  = (float*)(ws + o_dd);
  unsigned short* yB   = (unsigned short*)(ws + o_y);
  unsigned short* comb = (unsigned short*)(ws + o_comb);
  float*          outp = (float*)(ws + o_outp);
  int*            lens = (int*)(ws + o_len);

  k_convert<<<(W1N + W2N) / 256, 256, 0, stream>>>(in_proj_w, out_proj_w, W1b, W2b);
  k_lengths<<<BSZ, 256, 0, stream>>>(msk, lens);

  k_ln_bf16<<<NTOK, 256, 0, stream>>>(hidden, hb);

  k_gemm_bt<<<dim3(NTOK / 128, DPROJ_PAD / 128), 256, 0, stream>>>(
      hb, W1b, zx, DMODEL, DMODEL, DMODEL, DPROJ_PAD);

  k_conv<<<2 * NTOK, 256, 0, stream>>>(
      zx, conv_w_f, conv_b_f, conv_w_r, conv_b_r, lens, xb);

  k_dtprep<<<32, 256, 0, stream>>>(
      zx, dt_bias_f, dt_bias_r, A_log_f, A_log_r, lens, ddg);

  k_scan<<<2 * BSZ * NHEADS, 256, 0, stream>>>(xb, ddg, D_f, D_r, yB);

  k_gate_combine<<<NTOK, 256, 0, stream>>>(zx, yB, norm_w_f, norm_w_r, lens, comb);

  k_gemm_bt<<<dim3(NTOK / 128, DMODEL / 128), 256, 0, stream>>>(
      comb, W2b, outp, DINNER, DINNER, DINNER, DMODEL);

  k_ln_f32<<<NTOK, 256, 0, stream>>>(outp, outF);

  (void)in_sizes; (void)n_in; (void)out_size; (void)ws_size;
}

// Round 7
// 347.414 us; speedup vs baseline: 1.1998x; 1.1998x over previous
//
#include <hip/hip_runtime.h>

// ---------------------------------------------------------------------------
// BiMamba2 (D_MODEL=1024, D_INNER=2048, NHEADS=32, HEADDIM=64, D_STATE=128,
// D_CONV=4, B=4, L=1024).  Pipeline:
//   ln1 -> (bf16) -> GEMM1 (in-proj, shared both dirs) -> conv (per dir,
//   16t-tiled) -> dtprep (wave-parallel) -> chunked MFMA scan (frag-linear
//   LDS, async-pipelined, xt prefetch) -> gate+RMS+combine -> GEMM2 -> ln2
// ---------------------------------------------------------------------------

#define BSZ 4
#define SEQ 1024
#define DMODEL 1024
#define DINNER 2048
#define NHEADS 32
#define HEADDIM 64
#define DSTATE 128
#define CONVDIM 2304            // DINNER + 2*DSTATE
#define DPROJ 4384              // 2*DINNER + 2*DSTATE + NHEADS
#define DPROJ_PAD 4480          // padded to multiple of 128
#define NTOK (BSZ*SEQ)          // 4096
#define EPSF 1e-5f
#define CH 32                   // scan chunk length
#define NCHK (SEQ/CH)           // 32 chunks

typedef float f32x4 __attribute__((ext_vector_type(4)));
typedef __bf16 bf16x8 __attribute__((ext_vector_type(8)));

__device__ __forceinline__ unsigned short f2bf(float f) {
  unsigned int x = __float_as_uint(f);
  unsigned int r = (x + 0x7fffu + ((x >> 16) & 1u)) >> 16;
  return (unsigned short)r;
}
__device__ __forceinline__ float bf2f(unsigned short u) {
  return __uint_as_float(((unsigned int)u) << 16);
}

__device__ __forceinline__ void async_load16(const void* g, void* l) {
  __builtin_amdgcn_global_load_lds(
      (const __attribute__((address_space(1))) void*)g,
      (__attribute__((address_space(3))) void*)l, 16, 0, 0);
}

// ---------------------------------------------------------------------------
// Prep: weight conversion (merged) + lengths
// ---------------------------------------------------------------------------
#define W1N (DPROJ_PAD * DMODEL)
#define W2N (DMODEL * DINNER)
__global__ void k_convert(const float* __restrict__ w1, const float* __restrict__ w2,
                          unsigned short* __restrict__ o1, unsigned short* __restrict__ o2) {
  int idx = blockIdx.x * 256 + threadIdx.x;
  if (idx < W1N) {
    int row = idx >> 10, col = idx & 1023;
    float v = (row < DPROJ) ? w1[(size_t)row * DMODEL + col] : 0.f;
    o1[idx] = f2bf(v);
  } else {
    int k = idx - W1N;
    o2[k] = f2bf(w2[k]);
  }
}
__global__ void k_lengths(const unsigned char* __restrict__ mask, int* __restrict__ lengths) {
  int b = blockIdx.x, tid = threadIdx.x;
  int cnt = 0;
  for (int k = 0; k < 4; ++k)
    cnt += (mask[(size_t)b * SEQ + tid + k * 256] == 0) ? 1 : 0;
  for (int o = 32; o > 0; o >>= 1) cnt += __shfl_down(cnt, o);
  __shared__ int red[4];
  if ((tid & 63) == 0) red[tid >> 6] = cnt;
  __syncthreads();
  if (tid == 0) lengths[b] = red[0] + red[1] + red[2] + red[3];
}

// ---------------------------------------------------------------------------
// LayerNorm (1024 wide) -> bf16 out
// ---------------------------------------------------------------------------
__global__ __launch_bounds__(256) void k_ln_bf16(const float* __restrict__ in,
                                                 unsigned short* __restrict__ out) {
  int row = blockIdx.x, tid = threadIdx.x;
  float4 v = ((const float4*)(in + (size_t)row * DMODEL))[tid];
  float s = v.x + v.y + v.z + v.w;
  float ss = v.x * v.x + v.y * v.y + v.z * v.z + v.w * v.w;
  for (int o = 32; o > 0; o >>= 1) { s += __shfl_down(s, o); ss += __shfl_down(ss, o); }
  __shared__ float red[8];
  if ((tid & 63) == 0) { red[tid >> 6] = s; red[4 + (tid >> 6)] = ss; }
  __syncthreads();
  s = red[0] + red[1] + red[2] + red[3];
  ss = red[4] + red[5] + red[6] + red[7];
  float mu = s * (1.f / DMODEL);
  float var = ss * (1.f / DMODEL) - mu * mu;
  float rs = rsqrtf(var + EPSF);
  ushort4 o;
  o.x = f2bf((v.x - mu) * rs); o.y = f2bf((v.y - mu) * rs);
  o.z = f2bf((v.z - mu) * rs); o.w = f2bf((v.w - mu) * rs);
  ((ushort4*)(out + (size_t)row * DMODEL))[tid] = o;
}

// LayerNorm (1024 wide) -> fp32 out (final)
__global__ __launch_bounds__(256) void k_ln_f32(const float* __restrict__ in,
                                                float* __restrict__ out) {
  int row = blockIdx.x, tid = threadIdx.x;
  float4 v = ((const float4*)(in + (size_t)row * DMODEL))[tid];
  float s = v.x + v.y + v.z + v.w;
  float ss = v.x * v.x + v.y * v.y + v.z * v.z + v.w * v.w;
  for (int o = 32; o > 0; o >>= 1) { s += __shfl_down(s, o); ss += __shfl_down(ss, o); }
  __shared__ float red[8];
  if ((tid & 63) == 0) { red[tid >> 6] = s; red[4 + (tid >> 6)] = ss; }
  __syncthreads();
  s = red[0] + red[1] + red[2] + red[3];
  ss = red[4] + red[5] + red[6] + red[7];
  float mu = s * (1.f / DMODEL);
  float var = ss * (1.f / DMODEL) - mu * mu;
  float rs = rsqrtf(var + EPSF);
  float4 o;
  o.x = (v.x - mu) * rs; o.y = (v.y - mu) * rs;
  o.z = (v.z - mu) * rs; o.w = (v.w - mu) * rs;
  ((float4*)(out + (size_t)row * DMODEL))[tid] = o;
}

// ---------------------------------------------------------------------------
// bf16 MFMA GEMM (B^T form): C[M,N] = A[M,K] * B[N,K]^T, fp32 out.
// ---------------------------------------------------------------------------
__global__ __launch_bounds__(256) void k_gemm_bt(const unsigned short* __restrict__ A,
                                                 const unsigned short* __restrict__ B,
                                                 float* __restrict__ C,
                                                 int K, int lda, int ldb, int ldc) {
  __shared__ unsigned short Asm[128 * 32];
  __shared__ unsigned short Bsm[128 * 32];
  const int tid = threadIdx.x;
  const int lane = tid & 63;
  const int w = tid >> 6;
  const int wm = w >> 1, wn = w & 1;
  const long m0 = (long)blockIdx.x * 128;
  const long n0 = (long)blockIdx.y * 128;

  const int sr = lane >> 2;
  const int sc = (lane & 3) * 8;
  const unsigned short* gA0 = A + (m0 + (w * 2 + 0) * 16 + sr) * (long)lda + sc;
  const unsigned short* gA1 = A + (m0 + (w * 2 + 1) * 16 + sr) * (long)lda + sc;
  const unsigned short* gB0 = B + (n0 + (w * 2 + 0) * 16 + sr) * (long)ldb + sc;
  const unsigned short* gB1 = B + (n0 + (w * 2 + 1) * 16 + sr) * (long)ldb + sc;
  unsigned short* lA0 = Asm + (w * 2 + 0) * 512;
  unsigned short* lA1 = Asm + (w * 2 + 1) * 512;
  unsigned short* lB0 = Bsm + (w * 2 + 0) * 512;
  unsigned short* lB1 = Bsm + (w * 2 + 1) * 512;

  f32x4 acc[4][4] = {};
  const int q8 = (lane >> 4) * 8;
  const int r16 = lane & 15;

  for (int k0 = 0; k0 < K; k0 += 32) {
    async_load16(gA0 + k0, lA0);
    async_load16(gA1 + k0, lA1);
    async_load16(gB0 + k0, lB0);
    async_load16(gB1 + k0, lB1);
    __syncthreads();
    bf16x8 af[4], bfr[4];
#pragma unroll
    for (int i = 0; i < 4; ++i)
      af[i] = *reinterpret_cast<const bf16x8*>(Asm + (wm * 64 + i * 16 + r16) * 32 + q8);
#pragma unroll
    for (int j = 0; j < 4; ++j)
      bfr[j] = *reinterpret_cast<const bf16x8*>(Bsm + (wn * 64 + j * 16 + r16) * 32 + q8);
#pragma unroll
    for (int i = 0; i < 4; ++i)
#pragma unroll
      for (int j = 0; j < 4; ++j)
        acc[i][j] = __builtin_amdgcn_mfma_f32_16x16x32_bf16(af[i], bfr[j], acc[i][j], 0, 0, 0);
    __syncthreads();
  }
  const int q = lane >> 4, cn = lane & 15;
#pragma unroll
  for (int i = 0; i < 4; ++i)
#pragma unroll
    for (int j = 0; j < 4; ++j) {
      long crow = m0 + wm * 64 + i * 16 + q * 4;
      long ccol = n0 + wn * 64 + j * 16 + cn;
#pragma unroll
      for (int r = 0; r < 4; ++r)
        C[(crow + r) * (long)ldc + ccol] = acc[i][j][r];
    }
}

// ---------------------------------------------------------------------------
// Depthwise causal conv (width 4) + SiLU over xBC slice -> bf16.
// 16 timesteps per block, sliding register window (read amp 4x -> 1.19x).
// ---------------------------------------------------------------------------
__global__ __launch_bounds__(256) void k_conv(
    const float* __restrict__ zx,
    const float* __restrict__ cw_f, const float* __restrict__ cb_f,
    const float* __restrict__ cw_r, const float* __restrict__ cb_r,
    const int* __restrict__ lengths,
    __bf16* __restrict__ xb) {
  const int bx = blockIdx.x;                // db*64 + tg
  const int tg = bx & 63;
  const int db = bx >> 6;
  const int b = db & 3;
  const int dir = db >> 2;
  const int tid = threadIdx.x;
  const int len = lengths[b];
  const int t0 = tg * 16;

  const float* cw = dir ? cw_r : cw_f;
  const float* cb = dir ? cb_r : cb_f;

  float w0[9], w1[9], w2[9], w3[9], bias[9];
  float r0[9], r1[9], r2[9], r3[9];
#pragma unroll
  for (int k = 0; k < 9; ++k) {
    int c = tid + k * 256;
    float4 w4 = *(const float4*)(cw + (size_t)c * 4);
    w0[k] = w4.x; w1[k] = w4.y; w2[k] = w4.z; w3[k] = w4.w;
    bias[k] = cb[c];
    r0[k] = 0.f; r1[k] = 0.f; r2[k] = 0.f;
  }
  auto rowptr = [&](int tt) -> const float* {
    int s = dir ? ((tt < len) ? (len - 1 - tt) : tt) : tt;
    return zx + ((size_t)b * SEQ + s) * DPROJ_PAD + DINNER;
  };
  if (t0 >= 3) {          // interior block: preload full window
    const float* ra = rowptr(t0 - 3);
    const float* rb = rowptr(t0 - 2);
    const float* rc = rowptr(t0 - 1);
#pragma unroll
    for (int k = 0; k < 9; ++k) {
      int c = tid + k * 256;
      r0[k] = ra[c]; r1[k] = rb[c]; r2[k] = rc[c];
    }
  }
  {
    const float* rp = rowptr(t0);
#pragma unroll
    for (int k = 0; k < 9; ++k) r3[k] = rp[tid + k * 256];
  }
  for (int j = 0; j < 16; ++j) {
    float r4[9];
    if (j < 15) {
      const float* rp = rowptr(t0 + j + 1);
#pragma unroll
      for (int k = 0; k < 9; ++k) r4[k] = rp[tid + k * 256];
    }
    __bf16* orow = xb + ((size_t)db * SEQ + t0 + j) * CONVDIM;
#pragma unroll
    for (int k = 0; k < 9; ++k) {
      float acc = bias[k];
      acc = fmaf(w0[k], r0[k], acc);
      acc = fmaf(w1[k], r1[k], acc);
      acc = fmaf(w2[k], r2[k], acc);
      acc = fmaf(w3[k], r3[k], acc);
      float sig = 1.f / (1.f + __expf(-acc));
      orow[tid + k * 256] = (__bf16)(acc * sig);
      r0[k] = r1[k]; r1[k] = r2[k]; r2[k] = r3[k]; r3[k] = r4[k];
    }
  }
}

// ---------------------------------------------------------------------------
// dt/decay table precompute.  One 32-lane group per (db,h,chunk): 8192
// groups, fully parallel (tables are chunk-local).
// Layout ddg[(db*32+h)*32 + chunk][128]: [0:32)=dt, [32:64)=cd=A*cum,
// [64:96)=W=dt*e^{A(cum31-cum)}, [96:128)=P=e^{A*cum}.
// ---------------------------------------------------------------------------
__global__ __launch_bounds__(256) void k_dtprep(
    const float* __restrict__ zx,
    const float* __restrict__ dtb_f, const float* __restrict__ dtb_r,
    const float* __restrict__ al_f, const float* __restrict__ al_r,
    const int* __restrict__ lengths, float* __restrict__ ddg) {
  const int task = (blockIdx.x * 256 + threadIdx.x) >> 5;  // (db*32+h)*32+chunk
  const int l32 = threadIdx.x & 31;
  const int chunk = task & 31, hh = (task >> 5) & 31, db = task >> 10;
  const int b = db & 3, dir = db >> 2;
  const int len = lengths[b];
  const float dtbv = (dir ? dtb_r : dtb_f)[hh];
  const float Ah = -__expf((dir ? al_r : al_f)[hh]);
  const int s = chunk * 32 + l32;
  const int sf = dir ? ((s < len) ? (len - 1 - s) : s) : s;
  float raw = zx[(size_t)(b * SEQ + sf) * DPROJ_PAD + DINNER + CONVDIM + hh] + dtbv;
  float d = (raw > 20.f) ? raw : log1pf(__expf(raw));
  float cum = d;
#pragma unroll
  for (int o = 1; o < 32; o <<= 1) {
    float v = __shfl_up(cum, o, 32);
    if (l32 >= o) cum += v;
  }
  float cum31 = __shfl(cum, 31, 32);
  float* o = ddg + (size_t)task * 128;
  o[l32]      = d;
  o[32 + l32] = Ah * cum;
  o[64 + l32] = d * __expf(Ah * (cum31 - cum));
  o[96 + l32] = __expf(Ah * cum);
}

// ---------------------------------------------------------------------------
// Chunked MFMA selective scan, frag-linear LDS edition (see R5 notes).
// One block per (dir,b,h): 256 blocks x 256 threads (4 waves).
// xt A-frag prefetched one chunk ahead (global loads off the critical path).
// ---------------------------------------------------------------------------
__global__ __launch_bounds__(256) void k_scan(
    const __bf16* __restrict__ xb, const float* __restrict__ ddg,
    const float* __restrict__ D_f, const float* __restrict__ D_r,
    unsigned short* __restrict__ y) {
  __shared__ __bf16 Crawf[2][4096];   // C frag-linear, 8 tiles (tt,kk)
  __shared__ __bf16 Brawf[2][4096];   // B frag-linear (B-as-rows x k=n)
  __shared__ __bf16 Braw2[2][4096];   // B row-major [s][n] (for BT repack)
  __shared__ __bf16 BTf[4096];        // B^T frag-linear, 8 tiles (ng)
  __shared__ float  ddL[2][128];      // dt/cd/W/P tables
  __shared__ __bf16 SL[1024];         // S frag-linear, 2 tiles (t-halves)
  __shared__ __bf16 HL[4][2048];      // per-wave H frag-linear, 4 tiles (kk)
  __shared__ __bf16 yO[2][32 * 72];   // y chunk [t][p], stride 72

  const int bx = blockIdx.x;          // db*32 + h
  const int h = bx & 31;
  const int db = bx >> 5;
  const int dir = db >> 2;
  const int tid = threadIdx.x;
  const int lane = tid & 63;
  const int w = tid >> 6;
  const int l15 = lane & 15;
  const int q = lane >> 4;

  const float Dh = (dir ? D_r : D_f)[h];
  const __bf16* xbase = xb + (size_t)db * SEQ * CONVDIM;
  const float* ddbase = ddg + (size_t)bx * NCHK * 128;
  unsigned short* ybase = y + (size_t)db * SEQ * DINNER + h * HEADDIM;

  for (int i = lane; i < 2048; i += 64) HL[w][i] = (__bf16)0.f;
  for (int i = tid; i < 1024; i += 256) SL[i] = (__bf16)0.f;

  f32x4 accH[8] = {};

  auto issue = [&](int c, int nb) {
    const __bf16* xr = xbase + (size_t)c * CH * CONVDIM;
#pragma unroll
    for (int k = 0; k < 2; ++k) {
      const int idx = w * 2 + k;              // 0..7
      const int P = idx * 64 + lane;
      const int tt = P >> 8, kk = (P >> 6) & 3, qq = (P >> 4) & 3, ll = P & 15;
      const __bf16* gB = xr + (size_t)(tt * 16 + ll) * CONVDIM + DINNER + kk * 32 + qq * 8;
      async_load16(gB, &Brawf[nb][idx * 512]);
      async_load16(gB + 128, &Crawf[nb][idx * 512]);
      const int s = P >> 4, n8 = P & 15;
      const __bf16* g2 = xr + (size_t)s * CONVDIM + DINNER + n8 * 8;
      async_load16(g2, &Braw2[nb][idx * 512]);
    }
    if (w == 3 && lane < 32)
      async_load16(ddbase + (size_t)c * 128 + lane * 4, &ddL[nb][0]);
  };

  auto load_xt = [&](int c) {
    bf16x8 v;
    const __bf16* gx = xbase + (size_t)(c * CH + q * 8) * CONVDIM + h * HEADDIM + w * 16 + l15;
#pragma unroll
    for (int j = 0; j < 8; ++j) v[j] = gx[(size_t)j * CONVDIM];
    return v;
  };

  issue(0, 0);
  bf16x8 xt = load_xt(0);
  __syncthreads();

  for (int c = 0; c < NCHK; ++c) {
    const int cb = c & 1, nb = cb ^ 1;

    // ---------------- phase 1 ----------------
    // flush previous chunk's y (coalesced)
    if (c > 0) {
      const int tf = tid >> 3, p8 = (tid & 7) * 8;
      bf16x8 vy = *(const bf16x8*)&yO[nb][tf * 72 + p8];
      *(bf16x8*)(ybase + (size_t)((c - 1) * CH + tf) * DINNER + p8) = vy;
    }

    // B^T repack from row-major Braw2 (column reads 2-way, b128 writes free)
    {
      const int n = tid & 127, sg = tid >> 7;
#pragma unroll
      for (int e = 0; e < 2; ++e) {
        const int qp = sg * 2 + e;            // q' = s>>3
        bf16x8 v;
#pragma unroll
        for (int j = 0; j < 8; ++j) v[j] = Braw2[cb][(qp * 8 + j) * 128 + n];
        *(bf16x8*)&BTf[((n >> 4) * 64 + qp * 16 + (n & 15)) * 8] = v;
      }
    }

    // C frags (all waves, reused in y_inter); G quadrant + mask (waves 0-2)
    bf16x8 Cf0[4], Cf1[4];
#pragma unroll
    for (int kk = 0; kk < 4; ++kk) {
      Cf0[kk] = *(const bf16x8*)&Crawf[cb][(kk * 64 + lane) * 8];
      Cf1[kk] = *(const bf16x8*)&Crawf[cb][((4 + kk) * 64 + lane) * 8];
    }
    if (w < 3) {
      const int tt = (w == 0) ? 0 : 1;
      const int ss = (w == 2) ? 1 : 0;
      f32x4 G = {};
#pragma unroll
      for (int kk = 0; kk < 4; ++kk) {
        bf16x8 Bq = *(const bf16x8*)&Brawf[cb][((ss * 4 + kk) * 64 + lane) * 8];
        G = __builtin_amdgcn_mfma_f32_16x16x32_bf16(tt ? Cf1[kk] : Cf0[kk], Bq, G, 0, 0, 0);
      }
      const int sgl = ss * 16 + l15;
      const float sdt = ddL[cb][sgl];
      const float scd = ddL[cb][32 + sgl];
#pragma unroll
      for (int r = 0; r < 4; ++r) {
        const int t0 = q * 4 + r;
        float v = G[r] * sdt * __expf(ddL[cb][32 + tt * 16 + t0] - scd);
        if (tt == ss) {
          if (t0 < l15) v = 0.f;
          else if (t0 == l15) v += Dh;         // absorb D*x into S diagonal
        }
        SL[(tt * 64 + (ss * 2 + (l15 >> 3)) * 16 + t0) * 8 + (l15 & 7)] = (__bf16)v;
      }
    }
    __syncthreads();   // barrier A

    // ---------------- phase 2 ----------------
    if (c + 1 < NCHK) issue(c + 1, nb);       // overlap with compute below
    bf16x8 xt_n;
    if (c + 1 < NCHK) xt_n = load_xt(c + 1);  // prefetch, awaited next chunk

    // y_intra: y^T[p][t] = X^T @ S^T
    f32x4 accy0 = {}, accy1 = {};
    {
      bf16x8 S0 = *(const bf16x8*)&SL[(lane) * 8];
      bf16x8 S1 = *(const bf16x8*)&SL[(64 + lane) * 8];
      accy0 = __builtin_amdgcn_mfma_f32_16x16x32_bf16(xt, S0, accy0, 0, 0, 0);
      accy1 = __builtin_amdgcn_mfma_f32_16x16x32_bf16(xt, S1, accy1, 0, 0, 0);
    }
    // y_inter: (H_prev @ C^T) .* P_t
    {
      f32x4 ai0 = {}, ai1 = {};
#pragma unroll
      for (int kk = 0; kk < 4; ++kk) {
        bf16x8 Hf = *(const bf16x8*)&HL[w][(kk * 64 + lane) * 8];
        ai0 = __builtin_amdgcn_mfma_f32_16x16x32_bf16(Hf, Cf0[kk], ai0, 0, 0, 0);
        ai1 = __builtin_amdgcn_mfma_f32_16x16x32_bf16(Hf, Cf1[kk], ai1, 0, 0, 0);
      }
      const float P0 = ddL[cb][96 + l15], P1 = ddL[cb][96 + 16 + l15];
      accy0 = accy0 + ai0 * P0;
      accy1 = accy1 + ai1 * P1;
    }
    // H update: H = atot*H + (X.*W)^T @ B
    {
      const float atot = ddL[cb][96 + 31];
      bf16x8 xw;
#pragma unroll
      for (int j = 0; j < 8; ++j)
        xw[j] = (__bf16)((float)xt[j] * ddL[cb][64 + q * 8 + j]);
#pragma unroll
      for (int nt = 0; nt < 8; ++nt) {
        bf16x8 Bt = *(const bf16x8*)&BTf[(nt * 64 + lane) * 8];
        accH[nt] = accH[nt] * atot;
        accH[nt] = __builtin_amdgcn_mfma_f32_16x16x32_bf16(xw, Bt, accH[nt], 0, 0, 0);
      }
#pragma unroll
      for (int nt = 0; nt < 8; ++nt)
#pragma unroll
        for (int r = 0; r < 4; ++r) {
          const int n = nt * 16 + l15;
          HL[w][((n >> 5) * 64 + ((n & 31) >> 3) * 16 + q * 4 + r) * 8 + (n & 7)] =
              (__bf16)accH[nt][r];
        }
    }
    // stage y chunk (D*x already inside S diagonal)
#pragma unroll
    for (int r = 0; r < 4; ++r) {
      const int p = w * 16 + q * 4 + r;
      yO[cb][l15 * 72 + p]        = (__bf16)accy0[r];
      yO[cb][(16 + l15) * 72 + p] = (__bf16)accy1[r];
    }
    xt = xt_n;
    __syncthreads();   // barrier B (also drains async staging for c+1)
  }
  {  // final flush
    const int tf = tid >> 3, p8 = (tid & 7) * 8;
    bf16x8 vy = *(const bf16x8*)&yO[(NCHK - 1) & 1][tf * 72 + p8];
    *(bf16x8*)(ybase + (size_t)((NCHK - 1) * CH + tf) * DINNER + p8) = vy;
  }
}

// ---------------------------------------------------------------------------
// Gate (y * silu(z)) + RMSNorm per direction + average-with-flip -> bf16.
// ---------------------------------------------------------------------------
__global__ __launch_bounds__(256) void k_gate_combine(
    const float* __restrict__ zx, const unsigned short* __restrict__ y,
    const float* __restrict__ nw_f, const float* __restrict__ nw_r,
    const int* __restrict__ lengths, unsigned short* __restrict__ comb) {
  const int bx = blockIdx.x;            // b*SEQ + l
  const int b = bx >> 10, l = bx & 1023;
  const int tid = threadIdx.x;
  const int len = lengths[b];
  const int pos = (l < len) ? (len - 1 - l) : l;
  const float* z = zx + (size_t)bx * DPROJ_PAD;
  const unsigned short* yf = y + ((size_t)b * SEQ + l) * DINNER;
  const unsigned short* yr = y + ((size_t)(BSZ + b) * SEQ + pos) * DINNER;

  float gf[8], gr[8];
  float sf = 0.f, sr = 0.f;
#pragma unroll
  for (int k = 0; k < 8; ++k) {
    int c = tid + k * 256;
    float zz = z[c];
    float sz = zz / (1.f + __expf(-zz));
    float vf = bf2f(yf[c]) * sz;
    float vr = bf2f(yr[c]) * sz;
    gf[k] = vf; gr[k] = vr;
    sf += vf * vf; sr += vr * vr;
  }
  for (int o = 32; o > 0; o >>= 1) { sf += __shfl_down(sf, o); sr += __shfl_down(sr, o); }
  __shared__ float red[8];
  if ((tid & 63) == 0) { red[tid >> 6] = sf; red[4 + (tid >> 6)] = sr; }
  __syncthreads();
  sf = red[0] + red[1] + red[2] + red[3];
  sr = red[4] + red[5] + red[6] + red[7];
  float rf = rsqrtf(sf * (1.f / DINNER) + EPSF);
  float rr = rsqrtf(sr * (1.f / DINNER) + EPSF);
#pragma unroll
  for (int k = 0; k < 8; ++k) {
    int c = tid + k * 256;
    float o = 0.5f * (gf[k] * rf * nw_f[c] + gr[k] * rr * nw_r[c]);
    comb[(size_t)bx * DINNER + c] = f2bf(o);
  }
}

// ---------------------------------------------------------------------------
extern "C" void kernel_launch(void* const* d_in, const int* in_sizes, int n_in,
                              void* d_out, int out_size, void* d_ws, size_t ws_size,
                              hipStream_t stream) {
  const float* hidden      = (const float*)d_in[0];
  const unsigned char* msk = (const unsigned char*)d_in[1];
  const float* in_proj_w   = (const float*)d_in[2];
  const float* out_proj_w  = (const float*)d_in[3];
  const float* conv_w_f    = (const float*)d_in[4];
  const float* conv_b_f    = (const float*)d_in[5];
  const float* dt_bias_f   = (const float*)d_in[6];
  const float* A_log_f     = (const float*)d_in[7];
  const float* D_f         = (const float*)d_in[8];
  const float* norm_w_f    = (const float*)d_in[9];
  const float* conv_w_r    = (const float*)d_in[10];
  const float* conv_b_r    = (const float*)d_in[11];
  const float* dt_bias_r   = (const float*)d_in[12];
  const float* A_log_r     = (const float*)d_in[13];
  const float* D_r         = (const float*)d_in[14];
  const float* norm_w_r    = (const float*)d_in[15];
  float* outF = (float*)d_out;

  char* ws = (char*)d_ws;
  size_t o_w1b  = 0;                         // bf16 [4480][1024]
  size_t o_w2b  = o_w1b  + 9175040;          // bf16 [1024][2048]
  size_t o_hb   = o_w2b  + 4194304;          // bf16 [4096][1024]
  size_t o_zx   = o_hb   + 8388608;          // f32  [4096][4480]
  size_t o_xb   = o_zx   + 73400320;         // bf16 [2][4096][2304]
  size_t o_dd   = o_xb   + 37748736;         // f32  [8192][128]
  size_t o_y    = o_dd   + 4194304;          // bf16 [2][4096][2048]
  size_t o_comb = o_y    + 33554432;         // bf16 [4096][2048]
  size_t o_outp = o_comb + 16777216;         // f32  [4096][1024]
  size_t o_len  = o_outp + 16777216;         // int  [4]

  unsigned short* W1b  = (unsigned short*)(ws + o_w1b);
  unsigned short* W2b  = (unsigned short*)(ws + o_w2b);
  unsigned short* hb   = (unsigned short*)(ws + o_hb);
  float*          zx   = (float*)(ws + o_zx);
  __bf16*         xb   = (__bf16*)(ws + o_xb);
  float*          ddg  = (float*)(ws + o_dd);
  unsigned short* yB   = (unsigned short*)(ws + o_y);
  unsigned short* comb = (unsigned short*)(ws + o_comb);
  float*          outp = (float*)(ws + o_outp);
  int*            lens = (int*)(ws + o_len);

  k_convert<<<(W1N + W2N) / 256, 256, 0, stream>>>(in_proj_w, out_proj_w, W1b, W2b);
  k_lengths<<<BSZ, 256, 0, stream>>>(msk, lens);

  k_ln_bf16<<<NTOK, 256, 0, stream>>>(hidden, hb);

  k_gemm_bt<<<dim3(NTOK / 128, DPROJ_PAD / 128), 256, 0, stream>>>(
      hb, W1b, zx, DMODEL, DMODEL, DMODEL, DPROJ_PAD);

  k_conv<<<2 * BSZ * (SEQ / 16), 256, 0, stream>>>(
      zx, conv_w_f, conv_b_f, conv_w_r, conv_b_r, lens, xb);

  k_dtprep<<<1024, 256, 0, stream>>>(
      zx, dt_bias_f, dt_bias_r, A_log_f, A_log_r, lens, ddg);

  k_scan<<<2 * BSZ * NHEADS, 256, 0, stream>>>(xb, ddg, D_f, D_r, yB);

  k_gate_combine<<<NTOK, 256, 0, stream>>>(zx, yB, norm_w_f, norm_w_r, lens, comb);

  k_gemm_bt<<<dim3(NTOK / 128, DMODEL / 128), 256, 0, stream>>>(
      comb, W2b, outp, DINNER, DINNER, DINNER, DMODEL);

  k_ln_f32<<<NTOK, 256, 0, stream>>>(outp, outF);

  (void)in_sizes; (void)n_in; (void)out_size; (void)ws_size;
}

// Round 8
// 327.168 us; speedup vs baseline: 1.2741x; 1.0619x over previous
//
#include <hip/hip_runtime.h>

// ---------------------------------------------------------------------------
// BiMamba2 (D_MODEL=1024, D_INNER=2048, NHEADS=32, HEADDIM=64, D_STATE=128,
// D_CONV=4, B=4, L=1024).  Pipeline:
//   ln1 -> (bf16) -> GEMM1 (in-proj, bf16 out, shared both dirs) -> conv
//   (16t-tiled, bf16 in/out) -> dtprep (wave-parallel) -> chunked MFMA scan
//   (frag-linear LDS, single-buffered staging, 2 blocks/CU) ->
//   gate+RMS+combine -> GEMM2 -> ln2
// ---------------------------------------------------------------------------

#define BSZ 4
#define SEQ 1024
#define DMODEL 1024
#define DINNER 2048
#define NHEADS 32
#define HEADDIM 64
#define DSTATE 128
#define CONVDIM 2304            // DINNER + 2*DSTATE
#define DPROJ 4384              // 2*DINNER + 2*DSTATE + NHEADS
#define DPROJ_PAD 4480          // padded to multiple of 128
#define NTOK (BSZ*SEQ)          // 4096
#define EPSF 1e-5f
#define CH 32                   // scan chunk length
#define NCHK (SEQ/CH)           // 32 chunks

typedef float f32x4 __attribute__((ext_vector_type(4)));
typedef __bf16 bf16x8 __attribute__((ext_vector_type(8)));

__device__ __forceinline__ unsigned short f2bf(float f) {
  unsigned int x = __float_as_uint(f);
  unsigned int r = (x + 0x7fffu + ((x >> 16) & 1u)) >> 16;
  return (unsigned short)r;
}
__device__ __forceinline__ float bf2f(unsigned short u) {
  return __uint_as_float(((unsigned int)u) << 16);
}

__device__ __forceinline__ void async_load16(const void* g, void* l) {
  __builtin_amdgcn_global_load_lds(
      (const __attribute__((address_space(1))) void*)g,
      (__attribute__((address_space(3))) void*)l, 16, 0, 0);
}

// ---------------------------------------------------------------------------
// Prep: weight conversion (merged) + lengths
// ---------------------------------------------------------------------------
#define W1N (DPROJ_PAD * DMODEL)
#define W2N (DMODEL * DINNER)
__global__ void k_convert(const float* __restrict__ w1, const float* __restrict__ w2,
                          unsigned short* __restrict__ o1, unsigned short* __restrict__ o2) {
  int idx = blockIdx.x * 256 + threadIdx.x;
  if (idx < W1N) {
    int row = idx >> 10, col = idx & 1023;
    float v = (row < DPROJ) ? w1[(size_t)row * DMODEL + col] : 0.f;
    o1[idx] = f2bf(v);
  } else {
    int k = idx - W1N;
    o2[k] = f2bf(w2[k]);
  }
}
__global__ void k_lengths(const unsigned char* __restrict__ mask, int* __restrict__ lengths) {
  int b = blockIdx.x, tid = threadIdx.x;
  int cnt = 0;
  for (int k = 0; k < 4; ++k)
    cnt += (mask[(size_t)b * SEQ + tid + k * 256] == 0) ? 1 : 0;
  for (int o = 32; o > 0; o >>= 1) cnt += __shfl_down(cnt, o);
  __shared__ int red[4];
  if ((tid & 63) == 0) red[tid >> 6] = cnt;
  __syncthreads();
  if (tid == 0) lengths[b] = red[0] + red[1] + red[2] + red[3];
}

// ---------------------------------------------------------------------------
// LayerNorm (1024 wide) -> bf16 out
// ---------------------------------------------------------------------------
__global__ __launch_bounds__(256) void k_ln_bf16(const float* __restrict__ in,
                                                 unsigned short* __restrict__ out) {
  int row = blockIdx.x, tid = threadIdx.x;
  float4 v = ((const float4*)(in + (size_t)row * DMODEL))[tid];
  float s = v.x + v.y + v.z + v.w;
  float ss = v.x * v.x + v.y * v.y + v.z * v.z + v.w * v.w;
  for (int o = 32; o > 0; o >>= 1) { s += __shfl_down(s, o); ss += __shfl_down(ss, o); }
  __shared__ float red[8];
  if ((tid & 63) == 0) { red[tid >> 6] = s; red[4 + (tid >> 6)] = ss; }
  __syncthreads();
  s = red[0] + red[1] + red[2] + red[3];
  ss = red[4] + red[5] + red[6] + red[7];
  float mu = s * (1.f / DMODEL);
  float var = ss * (1.f / DMODEL) - mu * mu;
  float rs = rsqrtf(var + EPSF);
  ushort4 o;
  o.x = f2bf((v.x - mu) * rs); o.y = f2bf((v.y - mu) * rs);
  o.z = f2bf((v.z - mu) * rs); o.w = f2bf((v.w - mu) * rs);
  ((ushort4*)(out + (size_t)row * DMODEL))[tid] = o;
}

// LayerNorm (1024 wide) -> fp32 out (final)
__global__ __launch_bounds__(256) void k_ln_f32(const float* __restrict__ in,
                                                float* __restrict__ out) {
  int row = blockIdx.x, tid = threadIdx.x;
  float4 v = ((const float4*)(in + (size_t)row * DMODEL))[tid];
  float s = v.x + v.y + v.z + v.w;
  float ss = v.x * v.x + v.y * v.y + v.z * v.z + v.w * v.w;
  for (int o = 32; o > 0; o >>= 1) { s += __shfl_down(s, o); ss += __shfl_down(ss, o); }
  __shared__ float red[8];
  if ((tid & 63) == 0) { red[tid >> 6] = s; red[4 + (tid >> 6)] = ss; }
  __syncthreads();
  s = red[0] + red[1] + red[2] + red[3];
  ss = red[4] + red[5] + red[6] + red[7];
  float mu = s * (1.f / DMODEL);
  float var = ss * (1.f / DMODEL) - mu * mu;
  float rs = rsqrtf(var + EPSF);
  float4 o;
  o.x = (v.x - mu) * rs; o.y = (v.y - mu) * rs;
  o.z = (v.z - mu) * rs; o.w = (v.w - mu) * rs;
  ((float4*)(out + (size_t)row * DMODEL))[tid] = o;
}

// ---------------------------------------------------------------------------
// bf16 MFMA GEMM (B^T form): C[M,N] = A[M,K] * B[N,K]^T.
// Two epilogues: fp32 C (k_gemm_bt) and bf16 C (k_gemm_bt_h).
// ---------------------------------------------------------------------------
#define GEMM_BODY                                                              \
  __shared__ unsigned short Asm[128 * 32];                                     \
  __shared__ unsigned short Bsm[128 * 32];                                     \
  const int tid = threadIdx.x;                                                 \
  const int lane = tid & 63;                                                   \
  const int w = tid >> 6;                                                      \
  const int wm = w >> 1, wn = w & 1;                                           \
  const long m0 = (long)blockIdx.x * 128;                                      \
  const long n0 = (long)blockIdx.y * 128;                                      \
  const int sr = lane >> 2;                                                    \
  const int sc = (lane & 3) * 8;                                               \
  const unsigned short* gA0 = A + (m0 + (w * 2 + 0) * 16 + sr) * (long)lda + sc; \
  const unsigned short* gA1 = A + (m0 + (w * 2 + 1) * 16 + sr) * (long)lda + sc; \
  const unsigned short* gB0 = B + (n0 + (w * 2 + 0) * 16 + sr) * (long)ldb + sc; \
  const unsigned short* gB1 = B + (n0 + (w * 2 + 1) * 16 + sr) * (long)ldb + sc; \
  unsigned short* lA0 = Asm + (w * 2 + 0) * 512;                               \
  unsigned short* lA1 = Asm + (w * 2 + 1) * 512;                               \
  unsigned short* lB0 = Bsm + (w * 2 + 0) * 512;                               \
  unsigned short* lB1 = Bsm + (w * 2 + 1) * 512;                               \
  f32x4 acc[4][4] = {};                                                        \
  const int q8 = (lane >> 4) * 8;                                              \
  const int r16 = lane & 15;                                                   \
  for (int k0 = 0; k0 < K; k0 += 32) {                                         \
    async_load16(gA0 + k0, lA0);                                               \
    async_load16(gA1 + k0, lA1);                                               \
    async_load16(gB0 + k0, lB0);                                               \
    async_load16(gB1 + k0, lB1);                                               \
    __syncthreads();                                                           \
    bf16x8 af[4], bfr[4];                                                      \
    _Pragma("unroll")                                                          \
    for (int i = 0; i < 4; ++i)                                                \
      af[i] = *reinterpret_cast<const bf16x8*>(Asm + (wm * 64 + i * 16 + r16) * 32 + q8); \
    _Pragma("unroll")                                                          \
    for (int j = 0; j < 4; ++j)                                                \
      bfr[j] = *reinterpret_cast<const bf16x8*>(Bsm + (wn * 64 + j * 16 + r16) * 32 + q8); \
    _Pragma("unroll")                                                          \
    for (int i = 0; i < 4; ++i)                                                \
      _Pragma("unroll")                                                        \
      for (int j = 0; j < 4; ++j)                                              \
        acc[i][j] = __builtin_amdgcn_mfma_f32_16x16x32_bf16(af[i], bfr[j], acc[i][j], 0, 0, 0); \
    __syncthreads();                                                           \
  }                                                                            \
  const int q = lane >> 4, cn = lane & 15;

__global__ __launch_bounds__(256) void k_gemm_bt(const unsigned short* __restrict__ A,
                                                 const unsigned short* __restrict__ B,
                                                 float* __restrict__ C,
                                                 int K, int lda, int ldb, int ldc) {
  GEMM_BODY
#pragma unroll
  for (int i = 0; i < 4; ++i)
#pragma unroll
    for (int j = 0; j < 4; ++j) {
      long crow = m0 + wm * 64 + i * 16 + q * 4;
      long ccol = n0 + wn * 64 + j * 16 + cn;
#pragma unroll
      for (int r = 0; r < 4; ++r)
        C[(crow + r) * (long)ldc + ccol] = acc[i][j][r];
    }
}

__global__ __launch_bounds__(256) void k_gemm_bt_h(const unsigned short* __restrict__ A,
                                                   const unsigned short* __restrict__ B,
                                                   unsigned short* __restrict__ C,
                                                   int K, int lda, int ldb, int ldc) {
  GEMM_BODY
#pragma unroll
  for (int i = 0; i < 4; ++i)
#pragma unroll
    for (int j = 0; j < 4; ++j) {
      long crow = m0 + wm * 64 + i * 16 + q * 4;
      long ccol = n0 + wn * 64 + j * 16 + cn;
#pragma unroll
      for (int r = 0; r < 4; ++r)
        C[(crow + r) * (long)ldc + ccol] = f2bf(acc[i][j][r]);
    }
}

// ---------------------------------------------------------------------------
// Depthwise causal conv (width 4) + SiLU over xBC slice (bf16 in) -> bf16.
// 16 timesteps per block, sliding register window.
// ---------------------------------------------------------------------------
__global__ __launch_bounds__(256) void k_conv(
    const __bf16* __restrict__ zxb,
    const float* __restrict__ cw_f, const float* __restrict__ cb_f,
    const float* __restrict__ cw_r, const float* __restrict__ cb_r,
    const int* __restrict__ lengths,
    __bf16* __restrict__ xb) {
  const int bx = blockIdx.x;                // db*64 + tg
  const int tg = bx & 63;
  const int db = bx >> 6;
  const int b = db & 3;
  const int dir = db >> 2;
  const int tid = threadIdx.x;
  const int len = lengths[b];
  const int t0 = tg * 16;

  const float* cw = dir ? cw_r : cw_f;
  const float* cb = dir ? cb_r : cb_f;

  float w0[9], w1[9], w2[9], w3[9], bias[9];
  float r0[9], r1[9], r2[9], r3[9];
#pragma unroll
  for (int k = 0; k < 9; ++k) {
    int c = tid + k * 256;
    float4 w4 = *(const float4*)(cw + (size_t)c * 4);
    w0[k] = w4.x; w1[k] = w4.y; w2[k] = w4.z; w3[k] = w4.w;
    bias[k] = cb[c];
    r0[k] = 0.f; r1[k] = 0.f; r2[k] = 0.f;
  }
  auto rowptr = [&](int tt) -> const __bf16* {
    int s = dir ? ((tt < len) ? (len - 1 - tt) : tt) : tt;
    return zxb + ((size_t)b * SEQ + s) * DPROJ_PAD + DINNER;
  };
  if (t0 >= 3) {
    const __bf16* ra = rowptr(t0 - 3);
    const __bf16* rb = rowptr(t0 - 2);
    const __bf16* rc = rowptr(t0 - 1);
#pragma unroll
    for (int k = 0; k < 9; ++k) {
      int c = tid + k * 256;
      r0[k] = (float)ra[c]; r1[k] = (float)rb[c]; r2[k] = (float)rc[c];
    }
  }
  {
    const __bf16* rp = rowptr(t0);
#pragma unroll
    for (int k = 0; k < 9; ++k) r3[k] = (float)rp[tid + k * 256];
  }
  for (int j = 0; j < 16; ++j) {
    float r4[9];
    if (j < 15) {
      const __bf16* rp = rowptr(t0 + j + 1);
#pragma unroll
      for (int k = 0; k < 9; ++k) r4[k] = (float)rp[tid + k * 256];
    }
    __bf16* orow = xb + ((size_t)db * SEQ + t0 + j) * CONVDIM;
#pragma unroll
    for (int k = 0; k < 9; ++k) {
      float acc = bias[k];
      acc = fmaf(w0[k], r0[k], acc);
      acc = fmaf(w1[k], r1[k], acc);
      acc = fmaf(w2[k], r2[k], acc);
      acc = fmaf(w3[k], r3[k], acc);
      float sig = 1.f / (1.f + __expf(-acc));
      orow[tid + k * 256] = (__bf16)(acc * sig);
      r0[k] = r1[k]; r1[k] = r2[k]; r2[k] = r3[k]; r3[k] = r4[k];
    }
  }
}

// ---------------------------------------------------------------------------
// dt/decay table precompute.  One 32-lane group per (db,h,chunk): 8192
// groups.  Layout ddg[task][128]: dt / cd=A*cum / W / P.
// ---------------------------------------------------------------------------
__global__ __launch_bounds__(256) void k_dtprep(
    const __bf16* __restrict__ zxb,
    const float* __restrict__ dtb_f, const float* __restrict__ dtb_r,
    const float* __restrict__ al_f, const float* __restrict__ al_r,
    const int* __restrict__ lengths, float* __restrict__ ddg) {
  const int task = (blockIdx.x * 256 + threadIdx.x) >> 5;  // (db*32+h)*32+chunk
  const int l32 = threadIdx.x & 31;
  const int chunk = task & 31, hh = (task >> 5) & 31, db = task >> 10;
  const int b = db & 3, dir = db >> 2;
  const int len = lengths[b];
  const float dtbv = (dir ? dtb_r : dtb_f)[hh];
  const float Ah = -__expf((dir ? al_r : al_f)[hh]);
  const int s = chunk * 32 + l32;
  const int sf = dir ? ((s < len) ? (len - 1 - s) : s) : s;
  float raw = (float)zxb[(size_t)(b * SEQ + sf) * DPROJ_PAD + DINNER + CONVDIM + hh] + dtbv;
  float d = (raw > 20.f) ? raw : log1pf(__expf(raw));
  float cum = d;
#pragma unroll
  for (int o = 1; o < 32; o <<= 1) {
    float v = __shfl_up(cum, o, 32);
    if (l32 >= o) cum += v;
  }
  float cum31 = __shfl(cum, 31, 32);
  float* o = ddg + (size_t)task * 128;
  o[l32]      = d;
  o[32 + l32] = Ah * cum;
  o[64 + l32] = d * __expf(Ah * (cum31 - cum));
  o[96 + l32] = __expf(Ah * cum);
}

// ---------------------------------------------------------------------------
// Chunked MFMA selective scan, frag-linear LDS (see R5/R6 notes).
// Raw staging tiles (Crawf/Brawf/Braw2) are SINGLE-buffered: their reads all
// happen before barrier A; issue(c+1) writes happen after barrier A; barrier
// B drains before the next chunk's reads.  LDS 84->60 KB => 2 blocks/CU.
// ---------------------------------------------------------------------------
__global__ __launch_bounds__(256, 2) void k_scan(
    const __bf16* __restrict__ xb, const float* __restrict__ ddg,
    const float* __restrict__ D_f, const float* __restrict__ D_r,
    unsigned short* __restrict__ y) {
  __shared__ __bf16 Crawf[4096];      // C frag-linear, 8 tiles (tt,kk)
  __shared__ __bf16 Brawf[4096];      // B frag-linear (B-as-rows x k=n)
  __shared__ __bf16 Braw2[4096];      // B row-major [s][n] (for BT repack)
  __shared__ __bf16 BTf[4096];        // B^T frag-linear, 8 tiles (ng)
  __shared__ float  ddL[2][128];      // dt/cd/W/P tables (double)
  __shared__ __bf16 SL[1024];         // S frag-linear, 2 tiles (t-halves)
  __shared__ __bf16 HL[4][2048];      // per-wave H frag-linear, 4 tiles (kk)
  __shared__ __bf16 yO[2][32 * 72];   // y chunk [t][p], stride 72 (double)

  const int bx = blockIdx.x;          // db*32 + h
  const int h = bx & 31;
  const int db = bx >> 5;
  const int dir = db >> 2;
  const int tid = threadIdx.x;
  const int lane = tid & 63;
  const int w = tid >> 6;
  const int l15 = lane & 15;
  const int q = lane >> 4;

  const float Dh = (dir ? D_r : D_f)[h];
  const __bf16* xbase = xb + (size_t)db * SEQ * CONVDIM;
  const float* ddbase = ddg + (size_t)bx * NCHK * 128;
  unsigned short* ybase = y + (size_t)db * SEQ * DINNER + h * HEADDIM;

  for (int i = lane; i < 2048; i += 64) HL[w][i] = (__bf16)0.f;
  for (int i = tid; i < 1024; i += 256) SL[i] = (__bf16)0.f;

  f32x4 accH[8] = {};

  auto issue = [&](int c, int nb) {
    const __bf16* xr = xbase + (size_t)c * CH * CONVDIM;
#pragma unroll
    for (int k = 0; k < 2; ++k) {
      const int idx = w * 2 + k;              // 0..7
      const int P = idx * 64 + lane;
      const int tt = P >> 8, kk = (P >> 6) & 3, qq = (P >> 4) & 3, ll = P & 15;
      const __bf16* gB = xr + (size_t)(tt * 16 + ll) * CONVDIM + DINNER + kk * 32 + qq * 8;
      async_load16(gB, &Brawf[idx * 512]);
      async_load16(gB + 128, &Crawf[idx * 512]);
      const int s = P >> 4, n8 = P & 15;
      const __bf16* g2 = xr + (size_t)s * CONVDIM + DINNER + n8 * 8;
      async_load16(g2, &Braw2[idx * 512]);
    }
    if (w == 3 && lane < 32)
      async_load16(ddbase + (size_t)c * 128 + lane * 4, &ddL[nb][0]);
  };

  auto load_xt = [&](int c) {
    bf16x8 v;
    const __bf16* gx = xbase + (size_t)(c * CH + q * 8) * CONVDIM + h * HEADDIM + w * 16 + l15;
#pragma unroll
    for (int j = 0; j < 8; ++j) v[j] = gx[(size_t)j * CONVDIM];
    return v;
  };

  issue(0, 0);
  bf16x8 xt = load_xt(0);
  __syncthreads();

  for (int c = 0; c < NCHK; ++c) {
    const int cb = c & 1, nb = cb ^ 1;

    // ---------------- phase 1 (reads of raw staging buffers) ----------------
    if (c > 0) {   // flush previous chunk's y (coalesced)
      const int tf = tid >> 3, p8 = (tid & 7) * 8;
      bf16x8 vy = *(const bf16x8*)&yO[nb][tf * 72 + p8];
      *(bf16x8*)(ybase + (size_t)((c - 1) * CH + tf) * DINNER + p8) = vy;
    }

    // B^T repack from row-major Braw2
    {
      const int n = tid & 127, sg = tid >> 7;
#pragma unroll
      for (int e = 0; e < 2; ++e) {
        const int qp = sg * 2 + e;            // q' = s>>3
        bf16x8 v;
#pragma unroll
        for (int j = 0; j < 8; ++j) v[j] = Braw2[(qp * 8 + j) * 128 + n];
        *(bf16x8*)&BTf[((n >> 4) * 64 + qp * 16 + (n & 15)) * 8] = v;
      }
    }

    // C frags (all waves); G quadrant + mask (waves 0-2)
    bf16x8 Cf0[4], Cf1[4];
#pragma unroll
    for (int kk = 0; kk < 4; ++kk) {
      Cf0[kk] = *(const bf16x8*)&Crawf[(kk * 64 + lane) * 8];
      Cf1[kk] = *(const bf16x8*)&Crawf[((4 + kk) * 64 + lane) * 8];
    }
    if (w < 3) {
      const int tt = (w == 0) ? 0 : 1;
      const int ss = (w == 2) ? 1 : 0;
      f32x4 G = {};
#pragma unroll
      for (int kk = 0; kk < 4; ++kk) {
        bf16x8 Bq = *(const bf16x8*)&Brawf[((ss * 4 + kk) * 64 + lane) * 8];
        G = __builtin_amdgcn_mfma_f32_16x16x32_bf16(tt ? Cf1[kk] : Cf0[kk], Bq, G, 0, 0, 0);
      }
      const int sgl = ss * 16 + l15;
      const float sdt = ddL[cb][sgl];
      const float scd = ddL[cb][32 + sgl];
#pragma unroll
      for (int r = 0; r < 4; ++r) {
        const int t0 = q * 4 + r;
        float v = G[r] * sdt * __expf(ddL[cb][32 + tt * 16 + t0] - scd);
        if (tt == ss) {
          if (t0 < l15) v = 0.f;
          else if (t0 == l15) v += Dh;         // absorb D*x into S diagonal
        }
        SL[(tt * 64 + (ss * 2 + (l15 >> 3)) * 16 + t0) * 8 + (l15 & 7)] = (__bf16)v;
      }
    }
    __syncthreads();   // barrier A — raw-buffer reads complete block-wide

    // ---------------- phase 2 ----------------
    if (c + 1 < NCHK) issue(c + 1, nb);       // safe: single-buffer overwrite
    bf16x8 xt_n;
    if (c + 1 < NCHK) xt_n = load_xt(c + 1);

    // y_intra: y^T[p][t] = X^T @ S^T
    f32x4 accy0 = {}, accy1 = {};
    {
      bf16x8 S0 = *(const bf16x8*)&SL[(lane) * 8];
      bf16x8 S1 = *(const bf16x8*)&SL[(64 + lane) * 8];
      accy0 = __builtin_amdgcn_mfma_f32_16x16x32_bf16(xt, S0, accy0, 0, 0, 0);
      accy1 = __builtin_amdgcn_mfma_f32_16x16x32_bf16(xt, S1, accy1, 0, 0, 0);
    }
    // y_inter: (H_prev @ C^T) .* P_t
    {
      f32x4 ai0 = {}, ai1 = {};
#pragma unroll
      for (int kk = 0; kk < 4; ++kk) {
        bf16x8 Hf = *(const bf16x8*)&HL[w][(kk * 64 + lane) * 8];
        ai0 = __builtin_amdgcn_mfma_f32_16x16x32_bf16(Hf, Cf0[kk], ai0, 0, 0, 0);
        ai1 = __builtin_amdgcn_mfma_f32_16x16x32_bf16(Hf, Cf1[kk], ai1, 0, 0, 0);
      }
      const float P0 = ddL[cb][96 + l15], P1 = ddL[cb][96 + 16 + l15];
      accy0 = accy0 + ai0 * P0;
      accy1 = accy1 + ai1 * P1;
    }
    // H update: H = atot*H + (X.*W)^T @ B
    {
      const float atot = ddL[cb][96 + 31];
      bf16x8 xw;
#pragma unroll
      for (int j = 0; j < 8; ++j)
        xw[j] = (__bf16)((float)xt[j] * ddL[cb][64 + q * 8 + j]);
#pragma unroll
      for (int nt = 0; nt < 8; ++nt) {
        bf16x8 Bt = *(const bf16x8*)&BTf[(nt * 64 + lane) * 8];
        accH[nt] = accH[nt] * atot;
        accH[nt] = __builtin_amdgcn_mfma_f32_16x16x32_bf16(xw, Bt, accH[nt], 0, 0, 0);
      }
#pragma unroll
      for (int nt = 0; nt < 8; ++nt)
#pragma unroll
        for (int r = 0; r < 4; ++r) {
          const int n = nt * 16 + l15;
          HL[w][((n >> 5) * 64 + ((n & 31) >> 3) * 16 + q * 4 + r) * 8 + (n & 7)] =
              (__bf16)accH[nt][r];
        }
    }
    // stage y chunk
#pragma unroll
    for (int r = 0; r < 4; ++r) {
      const int p = w * 16 + q * 4 + r;
      yO[cb][l15 * 72 + p]        = (__bf16)accy0[r];
      yO[cb][(16 + l15) * 72 + p] = (__bf16)accy1[r];
    }
    xt = xt_n;
    __syncthreads();   // barrier B (drains async staging for c+1)
  }
  {  // final flush
    const int tf = tid >> 3, p8 = (tid & 7) * 8;
    bf16x8 vy = *(const bf16x8*)&yO[(NCHK - 1) & 1][tf * 72 + p8];
    *(bf16x8*)(ybase + (size_t)((NCHK - 1) * CH + tf) * DINNER + p8) = vy;
  }
}

// ---------------------------------------------------------------------------
// Gate (y * silu(z)) + RMSNorm per direction + average-with-flip -> bf16.
// ---------------------------------------------------------------------------
__global__ __launch_bounds__(256) void k_gate_combine(
    const __bf16* __restrict__ zxb, const unsigned short* __restrict__ y,
    const float* __restrict__ nw_f, const float* __restrict__ nw_r,
    const int* __restrict__ lengths, unsigned short* __restrict__ comb) {
  const int bx = blockIdx.x;            // b*SEQ + l
  const int b = bx >> 10, l = bx & 1023;
  const int tid = threadIdx.x;
  const int len = lengths[b];
  const int pos = (l < len) ? (len - 1 - l) : l;
  const __bf16* z = zxb + (size_t)bx * DPROJ_PAD;
  const unsigned short* yf = y + ((size_t)b * SEQ + l) * DINNER;
  const unsigned short* yr = y + ((size_t)(BSZ + b) * SEQ + pos) * DINNER;

  float gf[8], gr[8];
  float sf = 0.f, sr = 0.f;
#pragma unroll
  for (int k = 0; k < 8; ++k) {
    int c = tid + k * 256;
    float zz = (float)z[c];
    float sz = zz / (1.f + __expf(-zz));
    float vf = bf2f(yf[c]) * sz;
    float vr = bf2f(yr[c]) * sz;
    gf[k] = vf; gr[k] = vr;
    sf += vf * vf; sr += vr * vr;
  }
  for (int o = 32; o > 0; o >>= 1) { sf += __shfl_down(sf, o); sr += __shfl_down(sr, o); }
  __shared__ float red[8];
  if ((tid & 63) == 0) { red[tid >> 6] = sf; red[4 + (tid >> 6)] = sr; }
  __syncthreads();
  sf = red[0] + red[1] + red[2] + red[3];
  sr = red[4] + red[5] + red[6] + red[7];
  float rf = rsqrtf(sf * (1.f / DINNER) + EPSF);
  float rr = rsqrtf(sr * (1.f / DINNER) + EPSF);
#pragma unroll
  for (int k = 0; k < 8; ++k) {
    int c = tid + k * 256;
    float o = 0.5f * (gf[k] * rf * nw_f[c] + gr[k] * rr * nw_r[c]);
    comb[(size_t)bx * DINNER + c] = f2bf(o);
  }
}

// ---------------------------------------------------------------------------
extern "C" void kernel_launch(void* const* d_in, const int* in_sizes, int n_in,
                              void* d_out, int out_size, void* d_ws, size_t ws_size,
                              hipStream_t stream) {
  const float* hidden      = (const float*)d_in[0];
  const unsigned char* msk = (const unsigned char*)d_in[1];
  const float* in_proj_w   = (const float*)d_in[2];
  const float* out_proj_w  = (const float*)d_in[3];
  const float* conv_w_f    = (const float*)d_in[4];
  const float* conv_b_f    = (const float*)d_in[5];
  const float* dt_bias_f   = (const float*)d_in[6];
  const float* A_log_f     = (const float*)d_in[7];
  const float* D_f         = (const float*)d_in[8];
  const float* norm_w_f    = (const float*)d_in[9];
  const float* conv_w_r    = (const float*)d_in[10];
  const float* conv_b_r    = (const float*)d_in[11];
  const float* dt_bias_r   = (const float*)d_in[12];
  const float* A_log_r     = (const float*)d_in[13];
  const float* D_r         = (const float*)d_in[14];
  const float* norm_w_r    = (const float*)d_in[15];
  float* outF = (float*)d_out;

  char* ws = (char*)d_ws;
  size_t o_w1b  = 0;                         // bf16 [4480][1024]
  size_t o_w2b  = o_w1b  + 9175040;          // bf16 [1024][2048]
  size_t o_hb   = o_w2b  + 4194304;          // bf16 [4096][1024]
  size_t o_zx   = o_hb   + 8388608;          // bf16 [4096][4480]
  size_t o_xb   = o_zx   + 36700160;         // bf16 [2][4096][2304]
  size_t o_dd   = o_xb   + 37748736;         // f32  [8192][128]
  size_t o_y    = o_dd   + 4194304;          // bf16 [2][4096][2048]
  size_t o_comb = o_y    + 33554432;         // bf16 [4096][2048]
  size_t o_outp = o_comb + 16777216;         // f32  [4096][1024]
  size_t o_len  = o_outp + 16777216;         // int  [4]

  unsigned short* W1b  = (unsigned short*)(ws + o_w1b);
  unsigned short* W2b  = (unsigned short*)(ws + o_w2b);
  unsigned short* hb   = (unsigned short*)(ws + o_hb);
  __bf16*         zxb  = (__bf16*)(ws + o_zx);
  __bf16*         xb   = (__bf16*)(ws + o_xb);
  float*          ddg  = (float*)(ws + o_dd);
  unsigned short* yB   = (unsigned short*)(ws + o_y);
  unsigned short* comb = (unsigned short*)(ws + o_comb);
  float*          outp = (float*)(ws + o_outp);
  int*            lens = (int*)(ws + o_len);

  k_convert<<<(W1N + W2N) / 256, 256, 0, stream>>>(in_proj_w, out_proj_w, W1b, W2b);
  k_lengths<<<BSZ, 256, 0, stream>>>(msk, lens);

  k_ln_bf16<<<NTOK, 256, 0, stream>>>(hidden, hb);

  k_gemm_bt_h<<<dim3(NTOK / 128, DPROJ_PAD / 128), 256, 0, stream>>>(
      hb, W1b, (unsigned short*)zxb, DMODEL, DMODEL, DMODEL, DPROJ_PAD);

  k_conv<<<2 * BSZ * (SEQ / 16), 256, 0, stream>>>(
      zxb, conv_w_f, conv_b_f, conv_w_r, conv_b_r, lens, xb);

  k_dtprep<<<1024, 256, 0, stream>>>(
      zxb, dt_bias_f, dt_bias_r, A_log_f, A_log_r, lens, ddg);

  k_scan<<<2 * BSZ * NHEADS, 256, 0, stream>>>(xb, ddg, D_f, D_r, yB);

  k_gate_combine<<<NTOK, 256, 0, stream>>>(zxb, yB, norm_w_f, norm_w_r, lens, comb);

  k_gemm_bt<<<dim3(NTOK / 128, DMODEL / 128), 256, 0, stream>>>(
      comb, W2b, outp, DINNER, DINNER, DINNER, DMODEL);

  k_ln_f32<<<NTOK, 256, 0, stream>>>(outp, outF);

  (void)in_sizes; (void)n_in; (void)out_size; (void)ws_size;
}

// Round 9
// 312.235 us; speedup vs baseline: 1.3350x; 1.0478x over previous
//
#include <hip/hip_runtime.h>

// ---------------------------------------------------------------------------
// BiMamba2 (D_MODEL=1024, D_INNER=2048, NHEADS=32, HEADDIM=64, D_STATE=128,
// D_CONV=4, B=4, L=1024).  Pipeline:
//   ln1 -> (bf16) -> GEMM1 (in-proj, bf16 out, BK=64) -> conv (16t-tiled)
//   -> dtprep -> chunked MFMA scan (frag-linear LDS, 2 blocks/CU)
//   -> gate+RMS+combine -> GEMM2 (bf16 out, BK=64) -> ln2
// ---------------------------------------------------------------------------

#define BSZ 4
#define SEQ 1024
#define DMODEL 1024
#define DINNER 2048
#define NHEADS 32
#define HEADDIM 64
#define DSTATE 128
#define CONVDIM 2304            // DINNER + 2*DSTATE
#define DPROJ 4384              // 2*DINNER + 2*DSTATE + NHEADS
#define DPROJ_PAD 4480          // padded to multiple of 128
#define NTOK (BSZ*SEQ)          // 4096
#define EPSF 1e-5f
#define CH 32                   // scan chunk length
#define NCHK (SEQ/CH)           // 32 chunks

typedef float f32x4 __attribute__((ext_vector_type(4)));
typedef __bf16 bf16x8 __attribute__((ext_vector_type(8)));

__device__ __forceinline__ unsigned short f2bf(float f) {
  unsigned int x = __float_as_uint(f);
  unsigned int r = (x + 0x7fffu + ((x >> 16) & 1u)) >> 16;
  return (unsigned short)r;
}
__device__ __forceinline__ float bf2f(unsigned short u) {
  return __uint_as_float(((unsigned int)u) << 16);
}

__device__ __forceinline__ void async_load16(const void* g, void* l) {
  __builtin_amdgcn_global_load_lds(
      (const __attribute__((address_space(1))) void*)g,
      (__attribute__((address_space(3))) void*)l, 16, 0, 0);
}

// ---------------------------------------------------------------------------
// Prep: weight conversion (merged) + lengths
// ---------------------------------------------------------------------------
#define W1N (DPROJ_PAD * DMODEL)
#define W2N (DMODEL * DINNER)
__global__ void k_convert(const float* __restrict__ w1, const float* __restrict__ w2,
                          unsigned short* __restrict__ o1, unsigned short* __restrict__ o2) {
  int idx = blockIdx.x * 256 + threadIdx.x;
  if (idx < W1N) {
    int row = idx >> 10, col = idx & 1023;
    float v = (row < DPROJ) ? w1[(size_t)row * DMODEL + col] : 0.f;
    o1[idx] = f2bf(v);
  } else {
    int k = idx - W1N;
    o2[k] = f2bf(w2[k]);
  }
}
__global__ void k_lengths(const unsigned char* __restrict__ mask, int* __restrict__ lengths) {
  int b = blockIdx.x, tid = threadIdx.x;
  int cnt = 0;
  for (int k = 0; k < 4; ++k)
    cnt += (mask[(size_t)b * SEQ + tid + k * 256] == 0) ? 1 : 0;
  for (int o = 32; o > 0; o >>= 1) cnt += __shfl_down(cnt, o);
  __shared__ int red[4];
  if ((tid & 63) == 0) red[tid >> 6] = cnt;
  __syncthreads();
  if (tid == 0) lengths[b] = red[0] + red[1] + red[2] + red[3];
}

// ---------------------------------------------------------------------------
// LayerNorm (1024 wide, fp32 in) -> bf16 out
// ---------------------------------------------------------------------------
__global__ __launch_bounds__(256) void k_ln_bf16(const float* __restrict__ in,
                                                 unsigned short* __restrict__ out) {
  int row = blockIdx.x, tid = threadIdx.x;
  float4 v = ((const float4*)(in + (size_t)row * DMODEL))[tid];
  float s = v.x + v.y + v.z + v.w;
  float ss = v.x * v.x + v.y * v.y + v.z * v.z + v.w * v.w;
  for (int o = 32; o > 0; o >>= 1) { s += __shfl_down(s, o); ss += __shfl_down(ss, o); }
  __shared__ float red[8];
  if ((tid & 63) == 0) { red[tid >> 6] = s; red[4 + (tid >> 6)] = ss; }
  __syncthreads();
  s = red[0] + red[1] + red[2] + red[3];
  ss = red[4] + red[5] + red[6] + red[7];
  float mu = s * (1.f / DMODEL);
  float var = ss * (1.f / DMODEL) - mu * mu;
  float rs = rsqrtf(var + EPSF);
  ushort4 o;
  o.x = f2bf((v.x - mu) * rs); o.y = f2bf((v.y - mu) * rs);
  o.z = f2bf((v.z - mu) * rs); o.w = f2bf((v.w - mu) * rs);
  ((ushort4*)(out + (size_t)row * DMODEL))[tid] = o;
}

// LayerNorm (1024 wide, bf16 in) -> fp32 out (final)
__global__ __launch_bounds__(256) void k_ln_out(const unsigned short* __restrict__ in,
                                                float* __restrict__ out) {
  int row = blockIdx.x, tid = threadIdx.x;
  ushort4 u = ((const ushort4*)(in + (size_t)row * DMODEL))[tid];
  float4 v;
  v.x = bf2f(u.x); v.y = bf2f(u.y); v.z = bf2f(u.z); v.w = bf2f(u.w);
  float s = v.x + v.y + v.z + v.w;
  float ss = v.x * v.x + v.y * v.y + v.z * v.z + v.w * v.w;
  for (int o = 32; o > 0; o >>= 1) { s += __shfl_down(s, o); ss += __shfl_down(ss, o); }
  __shared__ float red[8];
  if ((tid & 63) == 0) { red[tid >> 6] = s; red[4 + (tid >> 6)] = ss; }
  __syncthreads();
  s = red[0] + red[1] + red[2] + red[3];
  ss = red[4] + red[5] + red[6] + red[7];
  float mu = s * (1.f / DMODEL);
  float var = ss * (1.f / DMODEL) - mu * mu;
  float rs = rsqrtf(var + EPSF);
  float4 o;
  o.x = (v.x - mu) * rs; o.y = (v.y - mu) * rs;
  o.z = (v.z - mu) * rs; o.w = (v.w - mu) * rs;
  ((float4*)(out + (size_t)row * DMODEL))[tid] = o;
}

// ---------------------------------------------------------------------------
// bf16 MFMA GEMM (B^T form): C[M,N] = A[M,K] * B[N,K]^T, bf16 out.
// BK=64 as two stacked BK=32 half-buffers: 32 MFMAs per barrier pair
// (AITER ratio), same per-half LDS layout/banking as the BK=32 version.
// Requires M%128==0, N%128==0, K%64==0.
// ---------------------------------------------------------------------------
__global__ __launch_bounds__(256) void k_gemm_bt_h(const unsigned short* __restrict__ A,
                                                   const unsigned short* __restrict__ B,
                                                   unsigned short* __restrict__ C,
                                                   int K, int lda, int ldb, int ldc) {
  __shared__ unsigned short Asm[2][128 * 32];
  __shared__ unsigned short Bsm[2][128 * 32];
  const int tid = threadIdx.x;
  const int lane = tid & 63;
  const int w = tid >> 6;
  const int wm = w >> 1, wn = w & 1;
  const long m0 = (long)blockIdx.x * 128;
  const long n0 = (long)blockIdx.y * 128;

  const int sr = lane >> 2;
  const int sc = (lane & 3) * 8;
  const unsigned short* gA0 = A + (m0 + (w * 2 + 0) * 16 + sr) * (long)lda + sc;
  const unsigned short* gA1 = A + (m0 + (w * 2 + 1) * 16 + sr) * (long)lda + sc;
  const unsigned short* gB0 = B + (n0 + (w * 2 + 0) * 16 + sr) * (long)ldb + sc;
  const unsigned short* gB1 = B + (n0 + (w * 2 + 1) * 16 + sr) * (long)ldb + sc;

  f32x4 acc[4][4] = {};
  const int q8 = (lane >> 4) * 8;
  const int r16 = lane & 15;

  for (int k0 = 0; k0 < K; k0 += 64) {
#pragma unroll
    for (int h = 0; h < 2; ++h) {
      const int ko = k0 + h * 32;
      async_load16(gA0 + ko, Asm[h] + (w * 2 + 0) * 512);
      async_load16(gA1 + ko, Asm[h] + (w * 2 + 1) * 512);
      async_load16(gB0 + ko, Bsm[h] + (w * 2 + 0) * 512);
      async_load16(gB1 + ko, Bsm[h] + (w * 2 + 1) * 512);
    }
    __syncthreads();
#pragma unroll
    for (int h = 0; h < 2; ++h) {
      bf16x8 af[4], bfr[4];
#pragma unroll
      for (int i = 0; i < 4; ++i)
        af[i] = *reinterpret_cast<const bf16x8*>(Asm[h] + (wm * 64 + i * 16 + r16) * 32 + q8);
#pragma unroll
      for (int j = 0; j < 4; ++j)
        bfr[j] = *reinterpret_cast<const bf16x8*>(Bsm[h] + (wn * 64 + j * 16 + r16) * 32 + q8);
#pragma unroll
      for (int i = 0; i < 4; ++i)
#pragma unroll
        for (int j = 0; j < 4; ++j)
          acc[i][j] = __builtin_amdgcn_mfma_f32_16x16x32_bf16(af[i], bfr[j], acc[i][j], 0, 0, 0);
    }
    __syncthreads();
  }
  const int q = lane >> 4, cn = lane & 15;
#pragma unroll
  for (int i = 0; i < 4; ++i)
#pragma unroll
    for (int j = 0; j < 4; ++j) {
      long crow = m0 + wm * 64 + i * 16 + q * 4;
      long ccol = n0 + wn * 64 + j * 16 + cn;
#pragma unroll
      for (int r = 0; r < 4; ++r)
        C[(crow + r) * (long)ldc + ccol] = f2bf(acc[i][j][r]);
    }
}

// ---------------------------------------------------------------------------
// Depthwise causal conv (width 4) + SiLU over xBC slice (bf16 in) -> bf16.
// 16 timesteps per block, sliding register window.
// ---------------------------------------------------------------------------
__global__ __launch_bounds__(256) void k_conv(
    const __bf16* __restrict__ zxb,
    const float* __restrict__ cw_f, const float* __restrict__ cb_f,
    const float* __restrict__ cw_r, const float* __restrict__ cb_r,
    const int* __restrict__ lengths,
    __bf16* __restrict__ xb) {
  const int bx = blockIdx.x;                // db*64 + tg
  const int tg = bx & 63;
  const int db = bx >> 6;
  const int b = db & 3;
  const int dir = db >> 2;
  const int tid = threadIdx.x;
  const int len = lengths[b];
  const int t0 = tg * 16;

  const float* cw = dir ? cw_r : cw_f;
  const float* cb = dir ? cb_r : cb_f;

  float w0[9], w1[9], w2[9], w3[9], bias[9];
  float r0[9], r1[9], r2[9], r3[9];
#pragma unroll
  for (int k = 0; k < 9; ++k) {
    int c = tid + k * 256;
    float4 w4 = *(const float4*)(cw + (size_t)c * 4);
    w0[k] = w4.x; w1[k] = w4.y; w2[k] = w4.z; w3[k] = w4.w;
    bias[k] = cb[c];
    r0[k] = 0.f; r1[k] = 0.f; r2[k] = 0.f;
  }
  auto rowptr = [&](int tt) -> const __bf16* {
    int s = dir ? ((tt < len) ? (len - 1 - tt) : tt) : tt;
    return zxb + ((size_t)b * SEQ + s) * DPROJ_PAD + DINNER;
  };
  if (t0 >= 3) {
    const __bf16* ra = rowptr(t0 - 3);
    const __bf16* rb = rowptr(t0 - 2);
    const __bf16* rc = rowptr(t0 - 1);
#pragma unroll
    for (int k = 0; k < 9; ++k) {
      int c = tid + k * 256;
      r0[k] = (float)ra[c]; r1[k] = (float)rb[c]; r2[k] = (float)rc[c];
    }
  }
  {
    const __bf16* rp = rowptr(t0);
#pragma unroll
    for (int k = 0; k < 9; ++k) r3[k] = (float)rp[tid + k * 256];
  }
  for (int j = 0; j < 16; ++j) {
    float r4[9];
    if (j < 15) {
      const __bf16* rp = rowptr(t0 + j + 1);
#pragma unroll
      for (int k = 0; k < 9; ++k) r4[k] = (float)rp[tid + k * 256];
    }
    __bf16* orow = xb + ((size_t)db * SEQ + t0 + j) * CONVDIM;
#pragma unroll
    for (int k = 0; k < 9; ++k) {
      float acc = bias[k];
      acc = fmaf(w0[k], r0[k], acc);
      acc = fmaf(w1[k], r1[k], acc);
      acc = fmaf(w2[k], r2[k], acc);
      acc = fmaf(w3[k], r3[k], acc);
      float sig = 1.f / (1.f + __expf(-acc));
      orow[tid + k * 256] = (__bf16)(acc * sig);
      r0[k] = r1[k]; r1[k] = r2[k]; r2[k] = r3[k]; r3[k] = r4[k];
    }
  }
}

// ---------------------------------------------------------------------------
// dt/decay table precompute.  One 32-lane group per (db,h,chunk): 8192
// groups.  Layout ddg[task][128]: dt / cd=A*cum / W / P.
// ---------------------------------------------------------------------------
__global__ __launch_bounds__(256) void k_dtprep(
    const __bf16* __restrict__ zxb,
    const float* __restrict__ dtb_f, const float* __restrict__ dtb_r,
    const float* __restrict__ al_f, const float* __restrict__ al_r,
    const int* __restrict__ lengths, float* __restrict__ ddg) {
  const int task = (blockIdx.x * 256 + threadIdx.x) >> 5;  // (db*32+h)*32+chunk
  const int l32 = threadIdx.x & 31;
  const int chunk = task & 31, hh = (task >> 5) & 31, db = task >> 10;
  const int b = db & 3, dir = db >> 2;
  const int len = lengths[b];
  const float dtbv = (dir ? dtb_r : dtb_f)[hh];
  const float Ah = -__expf((dir ? al_r : al_f)[hh]);
  const int s = chunk * 32 + l32;
  const int sf = dir ? ((s < len) ? (len - 1 - s) : s) : s;
  float raw = (float)zxb[(size_t)(b * SEQ + sf) * DPROJ_PAD + DINNER + CONVDIM + hh] + dtbv;
  float d = (raw > 20.f) ? raw : log1pf(__expf(raw));
  float cum = d;
#pragma unroll
  for (int o = 1; o < 32; o <<= 1) {
    float v = __shfl_up(cum, o, 32);
    if (l32 >= o) cum += v;
  }
  float cum31 = __shfl(cum, 31, 32);
  float* o = ddg + (size_t)task * 128;
  o[l32]      = d;
  o[32 + l32] = Ah * cum;
  o[64 + l32] = d * __expf(Ah * (cum31 - cum));
  o[96 + l32] = __expf(Ah * cum);
}

// ---------------------------------------------------------------------------
// Chunked MFMA selective scan, frag-linear LDS (see R5/R6/R7 notes).
// Single-buffered raw staging, 2 blocks/CU.
// ---------------------------------------------------------------------------
__global__ __launch_bounds__(256, 2) void k_scan(
    const __bf16* __restrict__ xb, const float* __restrict__ ddg,
    const float* __restrict__ D_f, const float* __restrict__ D_r,
    unsigned short* __restrict__ y) {
  __shared__ __bf16 Crawf[4096];      // C frag-linear, 8 tiles (tt,kk)
  __shared__ __bf16 Brawf[4096];      // B frag-linear (B-as-rows x k=n)
  __shared__ __bf16 Braw2[4096];      // B row-major [s][n] (for BT repack)
  __shared__ __bf16 BTf[4096];        // B^T frag-linear, 8 tiles (ng)
  __shared__ float  ddL[2][128];      // dt/cd/W/P tables (double)
  __shared__ __bf16 SL[1024];         // S frag-linear, 2 tiles (t-halves)
  __shared__ __bf16 HL[4][2048];      // per-wave H frag-linear, 4 tiles (kk)
  __shared__ __bf16 yO[2][32 * 72];   // y chunk [t][p], stride 72 (double)

  const int bx = blockIdx.x;          // db*32 + h
  const int h = bx & 31;
  const int db = bx >> 5;
  const int dir = db >> 2;
  const int tid = threadIdx.x;
  const int lane = tid & 63;
  const int w = tid >> 6;
  const int l15 = lane & 15;
  const int q = lane >> 4;

  const float Dh = (dir ? D_r : D_f)[h];
  const __bf16* xbase = xb + (size_t)db * SEQ * CONVDIM;
  const float* ddbase = ddg + (size_t)bx * NCHK * 128;
  unsigned short* ybase = y + (size_t)db * SEQ * DINNER + h * HEADDIM;

  for (int i = lane; i < 2048; i += 64) HL[w][i] = (__bf16)0.f;
  for (int i = tid; i < 1024; i += 256) SL[i] = (__bf16)0.f;

  f32x4 accH[8] = {};

  auto issue = [&](int c, int nb) {
    const __bf16* xr = xbase + (size_t)c * CH * CONVDIM;
#pragma unroll
    for (int k = 0; k < 2; ++k) {
      const int idx = w * 2 + k;              // 0..7
      const int P = idx * 64 + lane;
      const int tt = P >> 8, kk = (P >> 6) & 3, qq = (P >> 4) & 3, ll = P & 15;
      const __bf16* gB = xr + (size_t)(tt * 16 + ll) * CONVDIM + DINNER + kk * 32 + qq * 8;
      async_load16(gB, &Brawf[idx * 512]);
      async_load16(gB + 128, &Crawf[idx * 512]);
      const int s = P >> 4, n8 = P & 15;
      const __bf16* g2 = xr + (size_t)s * CONVDIM + DINNER + n8 * 8;
      async_load16(g2, &Braw2[idx * 512]);
    }
    if (w == 3 && lane < 32)
      async_load16(ddbase + (size_t)c * 128 + lane * 4, &ddL[nb][0]);
  };

  auto load_xt = [&](int c) {
    bf16x8 v;
    const __bf16* gx = xbase + (size_t)(c * CH + q * 8) * CONVDIM + h * HEADDIM + w * 16 + l15;
#pragma unroll
    for (int j = 0; j < 8; ++j) v[j] = gx[(size_t)j * CONVDIM];
    return v;
  };

  issue(0, 0);
  bf16x8 xt = load_xt(0);
  __syncthreads();

  for (int c = 0; c < NCHK; ++c) {
    const int cb = c & 1, nb = cb ^ 1;

    // ---------------- phase 1 (reads of raw staging buffers) ----------------
    if (c > 0) {   // flush previous chunk's y (coalesced)
      const int tf = tid >> 3, p8 = (tid & 7) * 8;
      bf16x8 vy = *(const bf16x8*)&yO[nb][tf * 72 + p8];
      *(bf16x8*)(ybase + (size_t)((c - 1) * CH + tf) * DINNER + p8) = vy;
    }

    // B^T repack from row-major Braw2
    {
      const int n = tid & 127, sg = tid >> 7;
#pragma unroll
      for (int e = 0; e < 2; ++e) {
        const int qp = sg * 2 + e;            // q' = s>>3
        bf16x8 v;
#pragma unroll
        for (int j = 0; j < 8; ++j) v[j] = Braw2[(qp * 8 + j) * 128 + n];
        *(bf16x8*)&BTf[((n >> 4) * 64 + qp * 16 + (n & 15)) * 8] = v;
      }
    }

    // C frags (all waves); G quadrant + mask (waves 0-2)
    bf16x8 Cf0[4], Cf1[4];
#pragma unroll
    for (int kk = 0; kk < 4; ++kk) {
      Cf0[kk] = *(const bf16x8*)&Crawf[(kk * 64 + lane) * 8];
      Cf1[kk] = *(const bf16x8*)&Crawf[((4 + kk) * 64 + lane) * 8];
    }
    if (w < 3) {
      const int tt = (w == 0) ? 0 : 1;
      const int ss = (w == 2) ? 1 : 0;
      f32x4 G = {};
#pragma unroll
      for (int kk = 0; kk < 4; ++kk) {
        bf16x8 Bq = *(const bf16x8*)&Brawf[((ss * 4 + kk) * 64 + lane) * 8];
        G = __builtin_amdgcn_mfma_f32_16x16x32_bf16(tt ? Cf1[kk] : Cf0[kk], Bq, G, 0, 0, 0);
      }
      const int sgl = ss * 16 + l15;
      const float sdt = ddL[cb][sgl];
      const float scd = ddL[cb][32 + sgl];
#pragma unroll
      for (int r = 0; r < 4; ++r) {
        const int t0 = q * 4 + r;
        float v = G[r] * sdt * __expf(ddL[cb][32 + tt * 16 + t0] - scd);
        if (tt == ss) {
          if (t0 < l15) v = 0.f;
          else if (t0 == l15) v += Dh;         // absorb D*x into S diagonal
        }
        SL[(tt * 64 + (ss * 2 + (l15 >> 3)) * 16 + t0) * 8 + (l15 & 7)] = (__bf16)v;
      }
    }
    __syncthreads();   // barrier A — raw-buffer reads complete block-wide

    // ---------------- phase 2 ----------------
    if (c + 1 < NCHK) issue(c + 1, nb);       // safe: single-buffer overwrite
    bf16x8 xt_n;
    if (c + 1 < NCHK) xt_n = load_xt(c + 1);

    // y_intra: y^T[p][t] = X^T @ S^T
    f32x4 accy0 = {}, accy1 = {};
    {
      bf16x8 S0 = *(const bf16x8*)&SL[(lane) * 8];
      bf16x8 S1 = *(const bf16x8*)&SL[(64 + lane) * 8];
      accy0 = __builtin_amdgcn_mfma_f32_16x16x32_bf16(xt, S0, accy0, 0, 0, 0);
      accy1 = __builtin_amdgcn_mfma_f32_16x16x32_bf16(xt, S1, accy1, 0, 0, 0);
    }
    // y_inter: (H_prev @ C^T) .* P_t
    {
      f32x4 ai0 = {}, ai1 = {};
#pragma unroll
      for (int kk = 0; kk < 4; ++kk) {
        bf16x8 Hf = *(const bf16x8*)&HL[w][(kk * 64 + lane) * 8];
        ai0 = __builtin_amdgcn_mfma_f32_16x16x32_bf16(Hf, Cf0[kk], ai0, 0, 0, 0);
        ai1 = __builtin_amdgcn_mfma_f32_16x16x32_bf16(Hf, Cf1[kk], ai1, 0, 0, 0);
      }
      const float P0 = ddL[cb][96 + l15], P1 = ddL[cb][96 + 16 + l15];
      accy0 = accy0 + ai0 * P0;
      accy1 = accy1 + ai1 * P1;
    }
    // H update: H = atot*H + (X.*W)^T @ B
    {
      const float atot = ddL[cb][96 + 31];
      bf16x8 xw;
#pragma unroll
      for (int j = 0; j < 8; ++j)
        xw[j] = (__bf16)((float)xt[j] * ddL[cb][64 + q * 8 + j]);
#pragma unroll
      for (int nt = 0; nt < 8; ++nt) {
        bf16x8 Bt = *(const bf16x8*)&BTf[(nt * 64 + lane) * 8];
        accH[nt] = accH[nt] * atot;
        accH[nt] = __builtin_amdgcn_mfma_f32_16x16x32_bf16(xw, Bt, accH[nt], 0, 0, 0);
      }
#pragma unroll
      for (int nt = 0; nt < 8; ++nt)
#pragma unroll
        for (int r = 0; r < 4; ++r) {
          const int n = nt * 16 + l15;
          HL[w][((n >> 5) * 64 + ((n & 31) >> 3) * 16 + q * 4 + r) * 8 + (n & 7)] =
              (__bf16)accH[nt][r];
        }
    }
    // stage y chunk
#pragma unroll
    for (int r = 0; r < 4; ++r) {
      const int p = w * 16 + q * 4 + r;
      yO[cb][l15 * 72 + p]        = (__bf16)accy0[r];
      yO[cb][(16 + l15) * 72 + p] = (__bf16)accy1[r];
    }
    xt = xt_n;
    __syncthreads();   // barrier B (drains async staging for c+1)
  }
  {  // final flush
    const int tf = tid >> 3, p8 = (tid & 7) * 8;
    bf16x8 vy = *(const bf16x8*)&yO[(NCHK - 1) & 1][tf * 72 + p8];
    *(bf16x8*)(ybase + (size_t)((NCHK - 1) * CH + tf) * DINNER + p8) = vy;
  }
}

// ---------------------------------------------------------------------------
// Gate (y * silu(z)) + RMSNorm per direction + average-with-flip -> bf16.
// ---------------------------------------------------------------------------
__global__ __launch_bounds__(256) void k_gate_combine(
    const __bf16* __restrict__ zxb, const unsigned short* __restrict__ y,
    const float* __restrict__ nw_f, const float* __restrict__ nw_r,
    const int* __restrict__ lengths, unsigned short* __restrict__ comb) {
  const int bx = blockIdx.x;            // b*SEQ + l
  const int b = bx >> 10, l = bx & 1023;
  const int tid = threadIdx.x;
  const int len = lengths[b];
  const int pos = (l < len) ? (len - 1 - l) : l;
  const __bf16* z = zxb + (size_t)bx * DPROJ_PAD;
  const unsigned short* yf = y + ((size_t)b * SEQ + l) * DINNER;
  const unsigned short* yr = y + ((size_t)(BSZ + b) * SEQ + pos) * DINNER;

  float gf[8], gr[8];
  float sf = 0.f, sr = 0.f;
#pragma unroll
  for (int k = 0; k < 8; ++k) {
    int c = tid + k * 256;
    float zz = (float)z[c];
    float sz = zz / (1.f + __expf(-zz));
    float vf = bf2f(yf[c]) * sz;
    float vr = bf2f(yr[c]) * sz;
    gf[k] = vf; gr[k] = vr;
    sf += vf * vf; sr += vr * vr;
  }
  for (int o = 32; o > 0; o >>= 1) { sf += __shfl_down(sf, o); sr += __shfl_down(sr, o); }
  __shared__ float red[8];
  if ((tid & 63) == 0) { red[tid >> 6] = sf; red[4 + (tid >> 6)] = sr; }
  __syncthreads();
  sf = red[0] + red[1] + red[2] + red[3];
  sr = red[4] + red[5] + red[6] + red[7];
  float rf = rsqrtf(sf * (1.f / DINNER) + EPSF);
  float rr = rsqrtf(sr * (1.f / DINNER) + EPSF);
#pragma unroll
  for (int k = 0; k < 8; ++k) {
    int c = tid + k * 256;
    float o = 0.5f * (gf[k] * rf * nw_f[c] + gr[k] * rr * nw_r[c]);
    comb[(size_t)bx * DINNER + c] = f2bf(o);
  }
}

// ---------------------------------------------------------------------------
extern "C" void kernel_launch(void* const* d_in, const int* in_sizes, int n_in,
                              void* d_out, int out_size, void* d_ws, size_t ws_size,
                              hipStream_t stream) {
  const float* hidden      = (const float*)d_in[0];
  const unsigned char* msk = (const unsigned char*)d_in[1];
  const float* in_proj_w   = (const float*)d_in[2];
  const float* out_proj_w  = (const float*)d_in[3];
  const float* conv_w_f    = (const float*)d_in[4];
  const float* conv_b_f    = (const float*)d_in[5];
  const float* dt_bias_f   = (const float*)d_in[6];
  const float* A_log_f     = (const float*)d_in[7];
  const float* D_f         = (const float*)d_in[8];
  const float* norm_w_f    = (const float*)d_in[9];
  const float* conv_w_r    = (const float*)d_in[10];
  const float* conv_b_r    = (const float*)d_in[11];
  const float* dt_bias_r   = (const float*)d_in[12];
  const float* A_log_r     = (const float*)d_in[13];
  const float* D_r         = (const float*)d_in[14];
  const float* norm_w_r    = (const float*)d_in[15];
  float* outF = (float*)d_out;

  char* ws = (char*)d_ws;
  size_t o_w1b  = 0;                         // bf16 [4480][1024]
  size_t o_w2b  = o_w1b  + 9175040;          // bf16 [1024][2048]
  size_t o_hb   = o_w2b  + 4194304;          // bf16 [4096][1024]
  size_t o_zx   = o_hb   + 8388608;          // bf16 [4096][4480]
  size_t o_xb   = o_zx   + 36700160;         // bf16 [2][4096][2304]
  size_t o_dd   = o_xb   + 37748736;         // f32  [8192][128]
  size_t o_y    = o_dd   + 4194304;          // bf16 [2][4096][2048]
  size_t o_comb = o_y    + 33554432;         // bf16 [4096][2048]
  size_t o_outp = o_comb + 16777216;         // bf16 [4096][1024]
  size_t o_len  = o_outp + 8388608;          // int  [4]

  unsigned short* W1b  = (unsigned short*)(ws + o_w1b);
  unsigned short* W2b  = (unsigned short*)(ws + o_w2b);
  unsigned short* hb   = (unsigned short*)(ws + o_hb);
  __bf16*         zxb  = (__bf16*)(ws + o_zx);
  __bf16*         xb   = (__bf16*)(ws + o_xb);
  float*          ddg  = (float*)(ws + o_dd);
  unsigned short* yB   = (unsigned short*)(ws + o_y);
  unsigned short* comb = (unsigned short*)(ws + o_comb);
  unsigned short* outp = (unsigned short*)(ws + o_outp);
  int*            lens = (int*)(ws + o_len);

  k_convert<<<(W1N + W2N) / 256, 256, 0, stream>>>(in_proj_w, out_proj_w, W1b, W2b);
  k_lengths<<<BSZ, 256, 0, stream>>>(msk, lens);

  k_ln_bf16<<<NTOK, 256, 0, stream>>>(hidden, hb);

  k_gemm_bt_h<<<dim3(NTOK / 128, DPROJ_PAD / 128), 256, 0, stream>>>(
      hb, W1b, (unsigned short*)zxb, DMODEL, DMODEL, DMODEL, DPROJ_PAD);

  k_conv<<<2 * BSZ * (SEQ / 16), 256, 0, stream>>>(
      zxb, conv_w_f, conv_b_f, conv_w_r, conv_b_r, lens, xb);

  k_dtprep<<<1024, 256, 0, stream>>>(
      zxb, dt_bias_f, dt_bias_r, A_log_f, A_log_r, lens, ddg);

  k_scan<<<2 * BSZ * NHEADS, 256, 0, stream>>>(xb, ddg, D_f, D_r, yB);

  k_gate_combine<<<NTOK, 256, 0, stream>>>(zxb, yB, norm_w_f, norm_w_r, lens, comb);

  k_gemm_bt_h<<<dim3(NTOK / 128, DMODEL / 128), 256, 0, stream>>>(
      comb, W2b, outp, DINNER, DINNER, DINNER, DMODEL);

  k_ln_out<<<NTOK, 256, 0, stream>>>(outp, outF);

  (void)in_sizes; (void)n_in; (void)out_size; (void)ws_size;
}